// Round 6
// baseline (2178630.859 us; speedup 1.0000x reference)
//
#include <hip/hip_runtime.h>
#include <hip/hip_bf16.h>

#define BB 64          // batch
#define TENC 512
#define ENCD 512
#define TDEC 600
#define MEL 80
#define RNN 1024
#define ATT 128
#define CC 32
#define KSZ 31
#define PADC 15
#define PRE 256
#define NWG 512

// ---- all scratch in __device__ globals ----
__device__ float g_dall[(size_t)TDEC * BB * PRE];   // prenet out, 39.3 MB
__device__ float g_pm[(size_t)BB * TENC * ATT];     // processed_memory, 16.8 MB
__device__ float g_part[8][BB][4096];               // split-K partials, 8 MB
__device__ float g_h1[2][BB * RNN];
__device__ float g_c1[BB * RNN];
__device__ float g_h2[2][BB * RNN];
__device__ float g_c2[BB * RNN];
__device__ float g_ctx[BB * ENCD];
__device__ float g_cum[BB * TENC];
__device__ float g_ebuf[BB * TENC];

// ---- grid barrier state ----
__device__ unsigned g_cnt = 0;
__device__ unsigned g_gen = 0;

__device__ __forceinline__ void grid_sync() {
  __syncthreads();
  if (threadIdx.x == 0) {
    unsigned gen = __hip_atomic_load(&g_gen, __ATOMIC_RELAXED, __HIP_MEMORY_SCOPE_AGENT);
    unsigned prev = __hip_atomic_fetch_add(&g_cnt, 1u, __ATOMIC_ACQ_REL, __HIP_MEMORY_SCOPE_AGENT);
    if (prev == NWG - 1) {
      __hip_atomic_store(&g_cnt, 0u, __ATOMIC_RELAXED, __HIP_MEMORY_SCOPE_AGENT);
      __hip_atomic_fetch_add(&g_gen, 1u, __ATOMIC_ACQ_REL, __HIP_MEMORY_SCOPE_AGENT);
    } else {
      int guard = 0;
      while (__hip_atomic_load(&g_gen, __ATOMIC_ACQUIRE, __HIP_MEMORY_SCOPE_AGENT) == gen) {
        __builtin_amdgcn_s_sleep(2);
        if (++guard > (1 << 22)) break;   // safety valve: never hang
      }
    }
  }
  __syncthreads();
}

union SMem {
  struct { float Al[64][68]; float Wl[64][68]; } gemm;                  // 34.8 KB
  struct { float xl[8 * 80]; float hl[8 * 256]; } prenet;               // 10.8 KB
  struct { float ml[8 * 512]; } pm;                                     // 16 KB
  struct {
    float cumext[TENC + 2 * PADC]; float h1l[RNN]; float pql[ATT];
    float pqp[ATT]; float cWl[CC * KSZ]; float lWl[CC * ATT]; float wl[ATT];
  } en;                                                                 // 28.2 KB
  struct { float pl[TENC]; float red[8]; float part[256]; } sm;         // 3.1 KB
  struct { float dh[RNN + ENCD]; } proj;                                // 6 KB
};

__device__ __forceinline__ float fast_tanh(float x) {
  x = fminf(15.f, fmaxf(-15.f, x));
  float e = __expf(2.f * x);
  return __fdividef(e - 1.f, e + 1.f);
}
__device__ __forceinline__ float fast_sig(float x) {
  x = fminf(30.f, fmaxf(-30.f, x));
  return __fdividef(1.f, 1.f + __expf(-x));
}

// ---------------- prenet job (one (b, t-chunk of 8)) ----------------
__device__ __forceinline__ void prenet_job(SMem& s, int j, int tid,
    const float* __restrict__ DT, const float* __restrict__ W0,
    const float* __restrict__ W1) {
  int b = j / 75, ch = j % 75, t0 = ch * 8;
  for (int i = tid; i < 8 * 80; i += 256) {
    int tt = i / 80, m = i % 80, t = t0 + tt;
    s.prenet.xl[i] = (t == 0) ? 0.f : DT[(size_t)b * (MEL * TDEC) + m * TDEC + (t - 1)];
  }
  __syncthreads();
  {
    float acc[8] = {0, 0, 0, 0, 0, 0, 0, 0};
    for (int m = 0; m < 80; ++m) {
      float w = W0[m * 256 + tid];
#pragma unroll
      for (int tt = 0; tt < 8; ++tt) acc[tt] += s.prenet.xl[tt * 80 + m] * w;
    }
    __syncthreads();
#pragma unroll
    for (int tt = 0; tt < 8; ++tt) s.prenet.hl[tt * 256 + tid] = fmaxf(acc[tt], 0.f);
  }
  __syncthreads();
  {
    float acc[8] = {0, 0, 0, 0, 0, 0, 0, 0};
    for (int jj = 0; jj < 256; ++jj) {
      float w = W1[jj * 256 + tid];
#pragma unroll
      for (int tt = 0; tt < 8; ++tt) acc[tt] += s.prenet.hl[tt * 256 + jj] * w;
    }
#pragma unroll
    for (int tt = 0; tt < 8; ++tt)
      g_dall[((size_t)(t0 + tt) * BB + b) * 256 + tid] = fmaxf(acc[tt], 0.f);
  }
}

// ---------------- processed_memory job (one (b, t-chunk of 8)) -------------
__device__ __forceinline__ void pm_job(SMem& s, int j, int tid,
    const float* __restrict__ mem, const float* __restrict__ mW) {
  int b = j >> 6, t0 = (j & 63) * 8;
  for (int i = tid; i < 8 * 512; i += 256) {
    int tt = i >> 9, d = i & 511;
    s.pm.ml[i] = mem[((size_t)b * TENC + t0 + tt) * ENCD + d];
  }
  __syncthreads();
  int a = tid & 127, th = tid >> 7;
  float acc[4] = {0, 0, 0, 0};
  for (int d = 0; d < 512; ++d) {
    float w = mW[d * 128 + a];
#pragma unroll
    for (int q = 0; q < 4; ++q) acc[q] += s.pm.ml[(th * 4 + q) * 512 + d] * w;
  }
#pragma unroll
  for (int q = 0; q < 4; ++q)
    g_pm[((size_t)b * TENC + t0 + th * 4 + q) * 128 + a] = acc[q];
}

// ---------------- split-K gates GEMM phase ----------------
// PHASE 1: jobs 0..447 (64 col-tiles x 7 K-slices of 256), K=1792
// PHASE 2: jobs 0..511 (64 col-tiles x 8 K-slices of 320), K=2560
template <int PHASE>
__device__ __forceinline__ void gemm_phase(SMem& s, int wg, int tid, int t,
    const float* __restrict__ Wih, const float* __restrict__ Whh,
    const float* __restrict__ h1p, const float* __restrict__ h1n,
    const float* __restrict__ h2p) {
  constexpr int KSLICE = (PHASE == 1) ? 256 : 320;
  constexpr int Kih = (PHASE == 1) ? 768 : 1536;
  const int nt = wg & 63;
  const int ks = wg >> 6;
  const int n0 = nt * 64;
  const int k0 = ks * KSLICE;
  const int rowq = tid & 15;
  const int colq = tid >> 4;
  float acc[4][4] = {};
  for (int kb = 0; kb < KSLICE; kb += 64) {
#pragma unroll
    for (int i = 0; i < 16; ++i) {
      int e = i * 256 + tid;
      int kk = e & 63, bb = e >> 6;
      int kg = k0 + kb + kk;
      float v;
      if (PHASE == 1) {
        if (kg < 256) v = g_dall[(size_t)t * BB * PRE + bb * PRE + kg];
        else if (kg < 768) v = g_ctx[bb * ENCD + (kg - 256)];
        else v = h1p[bb * RNN + (kg - 768)];
      } else {
        if (kg < 1024) v = h1n[bb * RNN + kg];
        else if (kg < 1536) v = g_ctx[bb * ENCD + (kg - 1024)];
        else v = h2p[bb * RNN + (kg - 1536)];
      }
      s.gemm.Al[kk][bb] = v;
    }
#pragma unroll
    for (int i = 0; i < 4; ++i) {
      int e = i * 256 + tid;
      int c4 = e & 15, kk = e >> 4;
      int kg = k0 + kb + kk;
      const float* src = (kg < Kih)
                             ? (Wih + (size_t)kg * 4096 + n0 + c4 * 4)
                             : (Whh + (size_t)(kg - Kih) * 4096 + n0 + c4 * 4);
      *(float4*)&s.gemm.Wl[kk][c4 * 4] = *(const float4*)src;
    }
    __syncthreads();
#pragma unroll 8
    for (int kk = 0; kk < 64; ++kk) {
      float4 a4 = *(float4*)&s.gemm.Al[kk][rowq * 4];
      float4 w4 = *(float4*)&s.gemm.Wl[kk][colq * 4];
      float av[4] = {a4.x, a4.y, a4.z, a4.w};
      float wv[4] = {w4.x, w4.y, w4.z, w4.w};
#pragma unroll
      for (int ii = 0; ii < 4; ++ii)
#pragma unroll
        for (int jj = 0; jj < 4; ++jj) acc[ii][jj] += av[ii] * wv[jj];
    }
    __syncthreads();
  }
#pragma unroll
  for (int ii = 0; ii < 4; ++ii) {
    float4 o = {acc[ii][0], acc[ii][1], acc[ii][2], acc[ii][3]};
    *(float4*)&g_part[ks][4 * rowq + ii][n0 + colq * 4] = o;
  }
}

// ---------------- split-K reduce + LSTM pointwise (jobs 0..255) ------------
__device__ __forceinline__ void reduce_lstm_job(int wg, int tid, int nsl,
    const float* __restrict__ bih, const float* __restrict__ bhh,
    float* __restrict__ c_st, float* __restrict__ h_out) {
  const int idx = wg * 256 + tid;
  const int b = idx >> 10;
  const int hcol = idx & 1023;
  float gi = 0.f, gf = 0.f, gg = 0.f, go = 0.f;
  for (int ks = 0; ks < nsl; ++ks) {
    const float* p = &g_part[ks][b][0];
    gi += p[hcol];
    gf += p[1024 + hcol];
    gg += p[2048 + hcol];
    go += p[3072 + hcol];
  }
  gi += bih[hcol] + bhh[hcol];
  gf += bih[1024 + hcol] + bhh[1024 + hcol];
  gg += bih[2048 + hcol] + bhh[2048 + hcol];
  go += bih[3072 + hcol] + bhh[3072 + hcol];
  float c_old = c_st[idx];
  float cn = fast_sig(gf) * c_old + fast_sig(gi) * fast_tanh(gg);
  c_st[idx] = cn;
  h_out[idx] = fast_sig(go) * fast_tanh(cn);
}

// ---------------- attention energies (jobs 0..127: b x half-T) -------------
__device__ __forceinline__ void energies_job(SMem& s, int wg, int tid,
    const float* __restrict__ h1, const float* __restrict__ qW,
    const float* __restrict__ convW, const float* __restrict__ locW,
    const float* __restrict__ wW, const float* __restrict__ wb,
    const int* __restrict__ mlen) {
  const int b = wg >> 1;
  const int t0 = (wg & 1) * 256;
  for (int i = tid; i < TENC; i += 256) s.en.cumext[PADC + i] = g_cum[b * TENC + i];
  if (tid < PADC) { s.en.cumext[tid] = 0.f; s.en.cumext[TENC + PADC + tid] = 0.f; }
  for (int i = tid; i < RNN; i += 256) s.en.h1l[i] = h1[b * RNN + i];
  for (int i = tid; i < CC * KSZ; i += 256) s.en.cWl[i] = convW[i];
  for (int i = tid; i < CC * ATT; i += 256) s.en.lWl[i] = locW[i];
  if (tid < ATT) s.en.wl[tid] = wW[tid];
  __syncthreads();
  {
    int a = tid & 127, kh = tid >> 7;
    float sacc = 0.f;
    for (int k = kh * 512; k < kh * 512 + 512; ++k)
      sacc += s.en.h1l[k] * qW[k * ATT + a];
    if (kh) s.en.pqp[a] = sacc;
    __syncthreads();
    if (!kh) s.en.pql[a] = sacc + s.en.pqp[a];
  }
  __syncthreads();
  const int t = t0 + tid;
  float win[KSZ];
#pragma unroll
  for (int k = 0; k < KSZ; ++k) win[k] = s.en.cumext[t0 + tid + k];
  float lc[CC];
#pragma unroll
  for (int c = 0; c < CC; ++c) {
    float v = 0.f;
#pragma unroll
    for (int k = 0; k < KSZ; ++k) v += win[k] * s.en.cWl[c * KSZ + k];
    lc[c] = v;
  }
  const float* pmrow = g_pm + ((size_t)b * TENC + t) * ATT;
  float e = 0.f;
  for (int a = 0; a < ATT; ++a) {
    float v = s.en.pql[a] + pmrow[a];
#pragma unroll
    for (int c = 0; c < CC; ++c) v += lc[c] * s.en.lWl[c * ATT + a];
    e += s.en.wl[a] * fast_tanh(v);
  }
  int len = mlen[b];
  g_ebuf[b * TENC + t] = (t >= len) ? -1e9f : (e + wb[0]);
}

// ---------------- softmax + ctx + cum + alignment (jobs 0..255) ------------
__device__ __forceinline__ void softmax_job(SMem& s, int wg, int tid,
    const float* __restrict__ memory, float* __restrict__ out_al, int t_step) {
  const int b = wg >> 2;
  const int q = wg & 3;
  float e0 = g_ebuf[b * TENC + tid], e1 = g_ebuf[b * TENC + 256 + tid];
  float m = fmaxf(e0, e1);
#pragma unroll
  for (int o = 32; o > 0; o >>= 1) m = fmaxf(m, __shfl_xor(m, o, 64));
  if ((tid & 63) == 0) s.sm.red[tid >> 6] = m;
  __syncthreads();
  float M = fmaxf(fmaxf(s.sm.red[0], s.sm.red[1]), fmaxf(s.sm.red[2], s.sm.red[3]));
  float p0 = __expf(e0 - M), p1 = __expf(e1 - M);
  s.sm.pl[tid] = p0;
  s.sm.pl[tid + 256] = p1;
  float sum = p0 + p1;
#pragma unroll
  for (int o = 32; o > 0; o >>= 1) sum += __shfl_xor(sum, o, 64);
  if ((tid & 63) == 0) s.sm.red[4 + (tid >> 6)] = sum;
  __syncthreads();
  float S = s.sm.red[4] + s.sm.red[5] + s.sm.red[6] + s.sm.red[7];
  float invS = __fdividef(1.f, S);
  if (q == 0) {
#pragma unroll
    for (int r = 0; r < 2; ++r) {
      int i = tid + r * 256;
      float av = s.sm.pl[i] * invS;
      out_al[(size_t)b * (TDEC * TENC) + (size_t)t_step * TENC + i] = av;
      g_cum[b * TENC + i] += av;
    }
  }
  const int dl = tid & 127, th = tid >> 7;
  const int d = q * 128 + dl;
  const float* mb = memory + (size_t)b * TENC * ENCD;
  float a0 = 0.f;
  for (int tt = th * 256; tt < th * 256 + 256; ++tt)
    a0 += s.sm.pl[tt] * mb[(size_t)tt * ENCD + d];
  s.sm.part[tid] = a0;
  __syncthreads();
  if (tid < 128)
    g_ctx[b * ENCD + q * 128 + tid] = (s.sm.part[tid] + s.sm.part[128 + tid]) * invS;
}

// ---------------- projection + gate (jobs 0..63: b) ----------------
__device__ __forceinline__ void proj_job(SMem& s, int b, int tid,
    const float* __restrict__ h2, const float* __restrict__ projW,
    const float* __restrict__ gateW, const float* __restrict__ gateB,
    float* __restrict__ out_mel, float* __restrict__ out_gate, int t_step) {
  for (int i = tid; i < RNN; i += 256) s.proj.dh[i] = h2[b * RNN + i];
  for (int i = tid; i < ENCD; i += 256) s.proj.dh[RNN + i] = g_ctx[b * ENCD + i];
  __syncthreads();
  if (tid < MEL) {
    float v = 0.f;
    for (int k = 0; k < RNN + ENCD; ++k) v += s.proj.dh[k] * projW[k * MEL + tid];
    out_mel[(size_t)b * (MEL * TDEC) + tid * TDEC + t_step] = v;
  } else if (tid == MEL) {
    float v = gateB[0];
    for (int k = 0; k < RNN + ENCD; ++k) v += s.proj.dh[k] * gateW[k];
    out_gate[b * TDEC + t_step] = v;
  }
}

// ---------------- the persistent mega-kernel ----------------
__global__ __launch_bounds__(256, 2) void k_mega(
    const float* __restrict__ memory, const int* __restrict__ mlen,
    const float* __restrict__ DT, const float* __restrict__ qW,
    const float* __restrict__ memW, const float* __restrict__ locW,
    const float* __restrict__ convW, const float* __restrict__ wW,
    const float* __restrict__ wb, const float* __restrict__ pW0,
    const float* __restrict__ pW1, const float* __restrict__ Wih1,
    const float* __restrict__ Whh1, const float* __restrict__ bih1,
    const float* __restrict__ bhh1, const float* __restrict__ Wih2,
    const float* __restrict__ Whh2, const float* __restrict__ bih2,
    const float* __restrict__ bhh2, const float* __restrict__ projW,
    const float* __restrict__ gateW, const float* __restrict__ gateB,
    float* __restrict__ out_mel, float* __restrict__ out_gate,
    float* __restrict__ out_al) {
  __shared__ SMem s;
  const int wg = blockIdx.x;
  const int tid = threadIdx.x;
  const int gid = wg * 256 + tid;

  // ---- pre-phase: init state + prenet + pm (no interdependence) ----
  {
    float* z1 = (float*)g_h1;  // 131072
    float* z2 = (float*)g_h2;  // 131072
    for (int i = gid; i < 2 * BB * RNN; i += NWG * 256) { z1[i] = 0.f; z2[i] = 0.f; }
    for (int i = gid; i < BB * RNN; i += NWG * 256) { g_c1[i] = 0.f; g_c2[i] = 0.f; }
    for (int i = gid; i < BB * ENCD; i += NWG * 256) g_ctx[i] = 0.f;
    for (int i = gid; i < BB * TENC; i += NWG * 256) g_cum[i] = 0.f;
  }
  for (int j = wg; j < 64 * 75; j += NWG) {
    prenet_job(s, j, tid, DT, pW0, pW1);
    __syncthreads();
  }
  for (int j = wg; j < 64 * 64; j += NWG) {
    pm_job(s, j, tid, memory, memW);
    __syncthreads();
  }
  grid_sync();

  // ---- 600 decoder steps ----
#pragma unroll 1
  for (int t = 0; t < TDEC; ++t) {
    const int pp = t & 1;
    const float* h1p = g_h1[pp];
    float* h1n = g_h1[1 - pp];
    const float* h2p = g_h2[pp];
    float* h2n = g_h2[1 - pp];

    // P1: gemm1 (448 WGs) || proj of step t-1 (64 WGs)
    if (wg < 448) gemm_phase<1>(s, wg, tid, t, Wih1, Whh1, h1p, nullptr, nullptr);
    else if (t > 0) proj_job(s, wg - 448, tid, h2p, projW, gateW, gateB, out_mel, out_gate, t - 1);
    grid_sync();

    // P2: reduce + lstm1 -> h1n
    if (wg < 256) reduce_lstm_job(wg, tid, 7, bih1, bhh1, g_c1, h1n);
    grid_sync();

    // P3: attention energies
    if (wg < 128) energies_job(s, wg, tid, h1n, qW, convW, locW, wW, wb, mlen);
    grid_sync();

    // P4: softmax + ctx + cum + alignment
    if (wg < 256) softmax_job(s, wg, tid, memory, out_al, t);
    grid_sync();

    // P5: gemm2 (512 WGs)
    gemm_phase<2>(s, wg, tid, t, Wih2, Whh2, h1p, h1n, h2p);
    grid_sync();

    // P6: reduce + lstm2 -> h2n
    if (wg < 256) reduce_lstm_job(wg, tid, 8, bih2, bhh2, g_c2, h2n);
    grid_sync();
  }

  // tail: proj of final step (h2n(599) = g_h2[0])
  if (wg < 64) proj_job(s, wg, tid, g_h2[0], projW, gateW, gateB, out_mel, out_gate, TDEC - 1);
}

extern "C" void kernel_launch(void* const* d_in, const int* in_sizes, int n_in,
                              void* d_out, int out_size, void* d_ws, size_t ws_size,
                              hipStream_t stream) {
  const float* memory = (const float*)d_in[0];
  const int* mlen = (const int*)d_in[1];
  const float* DT = (const float*)d_in[2];
  const float* qW = (const float*)d_in[3];
  const float* memW = (const float*)d_in[4];
  const float* locW = (const float*)d_in[5];
  const float* convW = (const float*)d_in[6];
  const float* wW = (const float*)d_in[7];
  const float* wb = (const float*)d_in[8];
  const float* pW0 = (const float*)d_in[9];
  const float* pW1 = (const float*)d_in[10];
  const float* Wih1 = (const float*)d_in[11];
  const float* Whh1 = (const float*)d_in[12];
  const float* bih1 = (const float*)d_in[13];
  const float* bhh1 = (const float*)d_in[14];
  const float* Wih2 = (const float*)d_in[15];
  const float* Whh2 = (const float*)d_in[16];
  const float* bih2 = (const float*)d_in[17];
  const float* bhh2 = (const float*)d_in[18];
  const float* projW = (const float*)d_in[19];
  const float* gateW = (const float*)d_in[20];
  const float* gateB = (const float*)d_in[21];
  (void)in_sizes; (void)n_in; (void)out_size; (void)d_ws; (void)ws_size;

  float* out_mel = (float*)d_out;
  float* out_gate = out_mel + (size_t)BB * MEL * TDEC;
  float* out_al = out_gate + (size_t)BB * TDEC;

  k_mega<<<NWG, 256, 0, stream>>>(memory, mlen, DT, qW, memW, locW, convW, wW,
                                  wb, pW0, pW1, Wih1, Whh1, bih1, bhh1, Wih2,
                                  Whh2, bih2, bhh2, projW, gateW, gateB,
                                  out_mel, out_gate, out_al);
}

// Round 7
// 667931.543 us; speedup vs baseline: 3.2618x; 3.2618x over previous
//
#include <hip/hip_runtime.h>
#include <hip/hip_bf16.h>

#define BB 64          // batch
#define TENC 512
#define ENCD 512
#define TDEC 600
#define MEL 80
#define RNN 1024
#define ATT 128
#define CC 32
#define KSZ 31
#define PADC 15
#define PRE 256
#define NWG 512

// ---- all scratch in __device__ globals ----
__device__ float g_dall[(size_t)TDEC * BB * PRE];   // prenet out, 39.3 MB
__device__ float g_pm[(size_t)BB * TENC * ATT];     // processed_memory, 16.8 MB
__device__ float g_part[16][BB][4096];              // split-K partials, 16.8 MB
__device__ float g_h1[2][BB * RNN];
__device__ float g_c1[BB * RNN];
__device__ float g_h2[2][BB * RNN];
__device__ float g_c2[BB * RNN];
__device__ float g_ctx[BB * ENCD];
__device__ float g_cum[BB * TENC];
__device__ float g_ebuf[BB * TENC];

// ---- grid barrier state ----
__device__ unsigned g_cnt = 0;
__device__ unsigned g_gen = 0;

// generation barrier. Arrival: one ACQ_REL RMW (builds the release chain).
// Wait: RELAXED polls (no cache invalidate per iteration!) + s_sleep, then a
// single ACQUIRE load to pull in remote writes. Leader: RELAXED cnt reset
// sequenced before one RELEASE store of gen+1.
__device__ __forceinline__ void grid_sync() {
  __syncthreads();
  if (threadIdx.x == 0) {
    unsigned gen = __hip_atomic_load(&g_gen, __ATOMIC_RELAXED, __HIP_MEMORY_SCOPE_AGENT);
    unsigned prev = __hip_atomic_fetch_add(&g_cnt, 1u, __ATOMIC_ACQ_REL, __HIP_MEMORY_SCOPE_AGENT);
    if (prev == NWG - 1) {
      __hip_atomic_store(&g_cnt, 0u, __ATOMIC_RELAXED, __HIP_MEMORY_SCOPE_AGENT);
      __hip_atomic_store(&g_gen, gen + 1u, __ATOMIC_RELEASE, __HIP_MEMORY_SCOPE_AGENT);
    } else {
      int guard = 0;
      while (__hip_atomic_load(&g_gen, __ATOMIC_RELAXED, __HIP_MEMORY_SCOPE_AGENT) == gen) {
        __builtin_amdgcn_s_sleep(16);
        if (++guard > (1 << 21)) break;   // safety valve: never hang
      }
      (void)__hip_atomic_load(&g_gen, __ATOMIC_ACQUIRE, __HIP_MEMORY_SCOPE_AGENT);
    }
  }
  __syncthreads();
}

union SMem {
  struct { float Al[64][68]; float Wl[64][68]; } gemm;                  // 34.8 KB
  struct { float xl[8 * 80]; float hl[8 * 256]; } prenet;               // 10.8 KB
  struct { float ml[8 * 512]; } pm;                                     // 16 KB
  struct {
    float cumext[TENC + 2 * PADC]; float h1l[RNN]; float pql[ATT];
    float pqp[ATT]; float cWl[CC * KSZ]; float lWl[CC * ATT]; float wl[ATT];
  } en;                                                                 // 28.2 KB
  struct { float pl[TENC]; float red[8]; float part[256]; } sm;         // 3.1 KB
  struct { float dh[RNN + ENCD]; } proj;                                // 6 KB
};

__device__ __forceinline__ float fast_tanh(float x) {
  x = fminf(15.f, fmaxf(-15.f, x));
  float e = __expf(2.f * x);
  return __fdividef(e - 1.f, e + 1.f);
}
__device__ __forceinline__ float fast_sig(float x) {
  x = fminf(30.f, fmaxf(-30.f, x));
  return __fdividef(1.f, 1.f + __expf(-x));
}

// ---------------- prenet job (one (b, t-chunk of 8)) ----------------
__device__ __forceinline__ void prenet_job(SMem& s, int j, int tid,
    const float* __restrict__ DT, const float* __restrict__ W0,
    const float* __restrict__ W1) {
  int b = j / 75, ch = j % 75, t0 = ch * 8;
  for (int i = tid; i < 8 * 80; i += 256) {
    int tt = i / 80, m = i % 80, t = t0 + tt;
    s.prenet.xl[i] = (t == 0) ? 0.f : DT[(size_t)b * (MEL * TDEC) + m * TDEC + (t - 1)];
  }
  __syncthreads();
  {
    float acc[8] = {0, 0, 0, 0, 0, 0, 0, 0};
    for (int m = 0; m < 80; ++m) {
      float w = W0[m * 256 + tid];
#pragma unroll
      for (int tt = 0; tt < 8; ++tt) acc[tt] += s.prenet.xl[tt * 80 + m] * w;
    }
    __syncthreads();
#pragma unroll
    for (int tt = 0; tt < 8; ++tt) s.prenet.hl[tt * 256 + tid] = fmaxf(acc[tt], 0.f);
  }
  __syncthreads();
  {
    float acc[8] = {0, 0, 0, 0, 0, 0, 0, 0};
    for (int jj = 0; jj < 256; ++jj) {
      float w = W1[jj * 256 + tid];
#pragma unroll
      for (int tt = 0; tt < 8; ++tt) acc[tt] += s.prenet.hl[tt * 256 + jj] * w;
    }
#pragma unroll
    for (int tt = 0; tt < 8; ++tt)
      g_dall[((size_t)(t0 + tt) * BB + b) * 256 + tid] = fmaxf(acc[tt], 0.f);
  }
}

// ---------------- processed_memory job (one (b, t-chunk of 8)) -------------
__device__ __forceinline__ void pm_job(SMem& s, int j, int tid,
    const float* __restrict__ mem, const float* __restrict__ mW) {
  int b = j >> 6, t0 = (j & 63) * 8;
  for (int i = tid; i < 8 * 512; i += 256) {
    int tt = i >> 9, d = i & 511;
    s.pm.ml[i] = mem[((size_t)b * TENC + t0 + tt) * ENCD + d];
  }
  __syncthreads();
  int a = tid & 127, th = tid >> 7;
  float acc[4] = {0, 0, 0, 0};
  for (int d = 0; d < 512; ++d) {
    float w = mW[d * 128 + a];
#pragma unroll
    for (int q = 0; q < 4; ++q) acc[q] += s.pm.ml[(th * 4 + q) * 512 + d] * w;
  }
#pragma unroll
  for (int q = 0; q < 4; ++q)
    g_pm[((size_t)b * TENC + t0 + th * 4 + q) * 128 + a] = acc[q];
}

// ---------------- split-K gates GEMM job ----------------
// Computes a 64(batch) x 64(col) tile over K range [k0, k0+ksl), partials to
// g_part[slot]. PHASE selects the A-source piecewise mapping.
template <int PHASE>
__device__ __forceinline__ void gemm_job(SMem& s, int tid, int nt, int slot,
    int k0, int ksl, int t, const float* __restrict__ Wih,
    const float* __restrict__ Whh, const float* __restrict__ h1p,
    const float* __restrict__ h1n, const float* __restrict__ h2p) {
  constexpr int Kih = (PHASE == 1) ? 768 : 1536;
  const int n0 = nt * 64;
  const int rowq = tid & 15;
  const int colq = tid >> 4;
  float acc[4][4] = {};
  for (int kb = 0; kb < ksl; kb += 64) {
#pragma unroll
    for (int i = 0; i < 16; ++i) {
      int e = i * 256 + tid;
      int kk = e & 63, bb = e >> 6;
      int kg = k0 + kb + kk;
      float v;
      if (PHASE == 1) {
        if (kg < 256) v = g_dall[(size_t)t * BB * PRE + bb * PRE + kg];
        else if (kg < 768) v = g_ctx[bb * ENCD + (kg - 256)];
        else v = h1p[bb * RNN + (kg - 768)];
      } else {
        if (kg < 1024) v = h1n[bb * RNN + kg];
        else if (kg < 1536) v = g_ctx[bb * ENCD + (kg - 1024)];
        else v = h2p[bb * RNN + (kg - 1536)];
      }
      s.gemm.Al[kk][bb] = v;
    }
#pragma unroll
    for (int i = 0; i < 4; ++i) {
      int e = i * 256 + tid;
      int c4 = e & 15, kk = e >> 4;
      int kg = k0 + kb + kk;
      const float* src = (kg < Kih)
                             ? (Wih + (size_t)kg * 4096 + n0 + c4 * 4)
                             : (Whh + (size_t)(kg - Kih) * 4096 + n0 + c4 * 4);
      *(float4*)&s.gemm.Wl[kk][c4 * 4] = *(const float4*)src;
    }
    __syncthreads();
#pragma unroll 8
    for (int kk = 0; kk < 64; ++kk) {
      float4 a4 = *(float4*)&s.gemm.Al[kk][rowq * 4];
      float4 w4 = *(float4*)&s.gemm.Wl[kk][colq * 4];
      float av[4] = {a4.x, a4.y, a4.z, a4.w};
      float wv[4] = {w4.x, w4.y, w4.z, w4.w};
#pragma unroll
      for (int ii = 0; ii < 4; ++ii)
#pragma unroll
        for (int jj = 0; jj < 4; ++jj) acc[ii][jj] += av[ii] * wv[jj];
    }
    __syncthreads();
  }
#pragma unroll
  for (int ii = 0; ii < 4; ++ii) {
    float4 o = {acc[ii][0], acc[ii][1], acc[ii][2], acc[ii][3]};
    *(float4*)&g_part[slot][4 * rowq + ii][n0 + colq * 4] = o;
  }
}

// ---------------- split-K reduce + LSTM pointwise (jobs 0..255) ------------
__device__ __forceinline__ void reduce_lstm_job(int wg, int tid, int first,
    int cnt, const float* __restrict__ bih, const float* __restrict__ bhh,
    float* __restrict__ c_st, float* __restrict__ h_out) {
  const int idx = wg * 256 + tid;
  const int b = idx >> 10;
  const int hcol = idx & 1023;
  float gi = 0.f, gf = 0.f, gg = 0.f, go = 0.f;
  for (int ks = first; ks < first + cnt; ++ks) {
    const float* p = &g_part[ks][b][0];
    gi += p[hcol];
    gf += p[1024 + hcol];
    gg += p[2048 + hcol];
    go += p[3072 + hcol];
  }
  gi += bih[hcol] + bhh[hcol];
  gf += bih[1024 + hcol] + bhh[1024 + hcol];
  gg += bih[2048 + hcol] + bhh[2048 + hcol];
  go += bih[3072 + hcol] + bhh[3072 + hcol];
  float c_old = c_st[idx];
  float cn = fast_sig(gf) * c_old + fast_sig(gi) * fast_tanh(gg);
  c_st[idx] = cn;
  h_out[idx] = fast_sig(go) * fast_tanh(cn);
}

// ---------------- attention energies (jobs 0..127: b x half-T) -------------
__device__ __forceinline__ void energies_job(SMem& s, int wg, int tid,
    const float* __restrict__ h1, const float* __restrict__ qW,
    const float* __restrict__ convW, const float* __restrict__ locW,
    const float* __restrict__ wW, const float* __restrict__ wb,
    const int* __restrict__ mlen) {
  const int b = wg >> 1;
  const int t0 = (wg & 1) * 256;
  for (int i = tid; i < TENC; i += 256) s.en.cumext[PADC + i] = g_cum[b * TENC + i];
  if (tid < PADC) { s.en.cumext[tid] = 0.f; s.en.cumext[TENC + PADC + tid] = 0.f; }
  for (int i = tid; i < RNN; i += 256) s.en.h1l[i] = h1[b * RNN + i];
  for (int i = tid; i < CC * KSZ; i += 256) s.en.cWl[i] = convW[i];
  for (int i = tid; i < CC * ATT; i += 256) s.en.lWl[i] = locW[i];
  if (tid < ATT) s.en.wl[tid] = wW[tid];
  __syncthreads();
  {
    int a = tid & 127, kh = tid >> 7;
    float sacc = 0.f;
    for (int k = kh * 512; k < kh * 512 + 512; ++k)
      sacc += s.en.h1l[k] * qW[k * ATT + a];
    if (kh) s.en.pqp[a] = sacc;
    __syncthreads();
    if (!kh) s.en.pql[a] = sacc + s.en.pqp[a];
  }
  __syncthreads();
  const int t = t0 + tid;
  float win[KSZ];
#pragma unroll
  for (int k = 0; k < KSZ; ++k) win[k] = s.en.cumext[t0 + tid + k];
  float lc[CC];
#pragma unroll
  for (int c = 0; c < CC; ++c) {
    float v = 0.f;
#pragma unroll
    for (int k = 0; k < KSZ; ++k) v += win[k] * s.en.cWl[c * KSZ + k];
    lc[c] = v;
  }
  const float* pmrow = g_pm + ((size_t)b * TENC + t) * ATT;
  float e = 0.f;
  for (int a = 0; a < ATT; ++a) {
    float v = s.en.pql[a] + pmrow[a];
#pragma unroll
    for (int c = 0; c < CC; ++c) v += lc[c] * s.en.lWl[c * ATT + a];
    e += s.en.wl[a] * fast_tanh(v);
  }
  int len = mlen[b];
  g_ebuf[b * TENC + t] = (t >= len) ? -1e9f : (e + wb[0]);
}

// ---------------- softmax + ctx + cum + alignment (jobs 0..255) ------------
__device__ __forceinline__ void softmax_job(SMem& s, int wg, int tid,
    const float* __restrict__ memory, float* __restrict__ out_al, int t_step) {
  const int b = wg >> 2;
  const int q = wg & 3;
  float e0 = g_ebuf[b * TENC + tid], e1 = g_ebuf[b * TENC + 256 + tid];
  float m = fmaxf(e0, e1);
#pragma unroll
  for (int o = 32; o > 0; o >>= 1) m = fmaxf(m, __shfl_xor(m, o, 64));
  if ((tid & 63) == 0) s.sm.red[tid >> 6] = m;
  __syncthreads();
  float M = fmaxf(fmaxf(s.sm.red[0], s.sm.red[1]), fmaxf(s.sm.red[2], s.sm.red[3]));
  float p0 = __expf(e0 - M), p1 = __expf(e1 - M);
  s.sm.pl[tid] = p0;
  s.sm.pl[tid + 256] = p1;
  float sum = p0 + p1;
#pragma unroll
  for (int o = 32; o > 0; o >>= 1) sum += __shfl_xor(sum, o, 64);
  if ((tid & 63) == 0) s.sm.red[4 + (tid >> 6)] = sum;
  __syncthreads();
  float S = s.sm.red[4] + s.sm.red[5] + s.sm.red[6] + s.sm.red[7];
  float invS = __fdividef(1.f, S);
  if (q == 0) {
#pragma unroll
    for (int r = 0; r < 2; ++r) {
      int i = tid + r * 256;
      float av = s.sm.pl[i] * invS;
      out_al[(size_t)b * (TDEC * TENC) + (size_t)t_step * TENC + i] = av;
      g_cum[b * TENC + i] += av;
    }
  }
  const int dl = tid & 127, th = tid >> 7;
  const int d = q * 128 + dl;
  const float* mb = memory + (size_t)b * TENC * ENCD;
  float a0 = 0.f;
  for (int tt = th * 256; tt < th * 256 + 256; ++tt)
    a0 += s.sm.pl[tt] * mb[(size_t)tt * ENCD + d];
  s.sm.part[tid] = a0;
  __syncthreads();
  if (tid < 128)
    g_ctx[b * ENCD + q * 128 + tid] = (s.sm.part[tid] + s.sm.part[128 + tid]) * invS;
}

// ---------------- projection + gate (jobs 0..63: b) ----------------
__device__ __forceinline__ void proj_job(SMem& s, int b, int tid,
    const float* __restrict__ h2, const float* __restrict__ projW,
    const float* __restrict__ gateW, const float* __restrict__ gateB,
    float* __restrict__ out_mel, float* __restrict__ out_gate, int t_step) {
  for (int i = tid; i < RNN; i += 256) s.proj.dh[i] = h2[b * RNN + i];
  for (int i = tid; i < ENCD; i += 256) s.proj.dh[RNN + i] = g_ctx[b * ENCD + i];
  __syncthreads();
  if (tid < MEL) {
    float v = 0.f;
    for (int k = 0; k < RNN + ENCD; ++k) v += s.proj.dh[k] * projW[k * MEL + tid];
    out_mel[(size_t)b * (MEL * TDEC) + tid * TDEC + t_step] = v;
  } else if (tid == MEL) {
    float v = gateB[0];
    for (int k = 0; k < RNN + ENCD; ++k) v += s.proj.dh[k] * gateW[k];
    out_gate[b * TDEC + t_step] = v;
  }
}

// ---------------- the persistent mega-kernel ----------------
// 5 barriers/step:
//  PA: gemm1(t) [256: 4 slices x 448K]           || reduce2(t-1)+lstm2 [256]
//  PB: reduce1(t)+lstm1 [256]                    || proj(t-1) [64]
//  PC: energies(t) [128]                         || gemm2 h2p-slices [256]
//  PD: softmax+ctx(t) [256]                      || gemm2 h1n-slices [256]
//  PE: gemm2 ctx-slices [256]
__global__ __launch_bounds__(256, 2) void k_mega(
    const float* __restrict__ memory, const int* __restrict__ mlen,
    const float* __restrict__ DT, const float* __restrict__ qW,
    const float* __restrict__ memW, const float* __restrict__ locW,
    const float* __restrict__ convW, const float* __restrict__ wW,
    const float* __restrict__ wb, const float* __restrict__ pW0,
    const float* __restrict__ pW1, const float* __restrict__ Wih1,
    const float* __restrict__ Whh1, const float* __restrict__ bih1,
    const float* __restrict__ bhh1, const float* __restrict__ Wih2,
    const float* __restrict__ Whh2, const float* __restrict__ bih2,
    const float* __restrict__ bhh2, const float* __restrict__ projW,
    const float* __restrict__ gateW, const float* __restrict__ gateB,
    float* __restrict__ out_mel, float* __restrict__ out_gate,
    float* __restrict__ out_al) {
  __shared__ SMem s;
  const int wg = blockIdx.x;
  const int tid = threadIdx.x;
  const int gid = wg * 256 + tid;

  // ---- pre-phase: init state + prenet + pm ----
  {
    float* z1 = (float*)g_h1;
    float* z2 = (float*)g_h2;
    for (int i = gid; i < 2 * BB * RNN; i += NWG * 256) { z1[i] = 0.f; z2[i] = 0.f; }
    for (int i = gid; i < BB * RNN; i += NWG * 256) { g_c1[i] = 0.f; g_c2[i] = 0.f; }
    for (int i = gid; i < BB * ENCD; i += NWG * 256) g_ctx[i] = 0.f;
    for (int i = gid; i < BB * TENC; i += NWG * 256) g_cum[i] = 0.f;
  }
  for (int j = wg; j < 64 * 75; j += NWG) {
    prenet_job(s, j, tid, DT, pW0, pW1);
    __syncthreads();
  }
  for (int j = wg; j < 64 * 64; j += NWG) {
    pm_job(s, j, tid, memory, memW);
    __syncthreads();
  }
  grid_sync();

  // ---- 600 decoder steps ----
#pragma unroll 1
  for (int t = 0; t < TDEC; ++t) {
    const int pp = t & 1;
    const float* h1p = g_h1[pp];
    float* h1n = g_h1[1 - pp];
    const float* h2p = g_h2[pp];   // = h2n(t-1), written in PA below

    // PA: gemm1 (all K ready: dall(t), ctx(t-1), h1n(t-1)) || reduce2(t-1)
    if (wg < 256) {
      gemm_job<1>(s, tid, wg & 63, wg >> 6, (wg >> 6) * 448, 448, t,
                  Wih1, Whh1, h1p, nullptr, nullptr);
    } else if (t > 0) {
      reduce_lstm_job(wg - 256, tid, 4, 12, bih2, bhh2, g_c2, g_h2[pp]);
    }
    grid_sync();

    // PB: reduce1 + lstm1 -> h1n(t) || proj(t-1) (h2n(t-1), ctx(t-1))
    if (wg < 256) {
      reduce_lstm_job(wg, tid, 0, 4, bih1, bhh1, g_c1, h1n);
    } else if (wg < 320 && t > 0) {
      proj_job(s, wg - 256, tid, h2p, projW, gateW, gateB, out_mel, out_gate, t - 1);
    }
    grid_sync();

    // PC: energies(t) || gemm2 h2p-slices (K 1536..2560)
    if (wg < 128) {
      energies_job(s, wg, tid, h1n, qW, convW, locW, wW, wb, mlen);
    } else if (wg < 384) {
      int w = wg - 128;
      gemm_job<2>(s, tid, w & 63, 4 + (w >> 6), 1536 + (w >> 6) * 256, 256, t,
                  Wih2, Whh2, nullptr, h1n, h2p);
    }
    grid_sync();

    // PD: softmax + ctx(t) || gemm2 h1n-slices (K 0..1024)
    if (wg < 256) {
      softmax_job(s, wg, tid, memory, out_al, t);
    } else {
      int w = wg - 256;
      gemm_job<2>(s, tid, w & 63, 8 + (w >> 6), (w >> 6) * 256, 256, t,
                  Wih2, Whh2, nullptr, h1n, h2p);
    }
    grid_sync();

    // PE: gemm2 ctx-slices (K 1024..1536)
    if (wg < 256) {
      gemm_job<2>(s, tid, wg & 63, 12 + (wg >> 6), 1024 + (wg >> 6) * 128, 128, t,
                  Wih2, Whh2, nullptr, h1n, h2p);
    }
    grid_sync();
  }

  // tail: reduce2(599) -> g_h2[0], then proj(599)
  if (wg < 256) reduce_lstm_job(wg, tid, 4, 12, bih2, bhh2, g_c2, g_h2[0]);
  grid_sync();
  if (wg < 64) proj_job(s, wg, tid, g_h2[0], projW, gateW, gateB, out_mel, out_gate, TDEC - 1);
}

extern "C" void kernel_launch(void* const* d_in, const int* in_sizes, int n_in,
                              void* d_out, int out_size, void* d_ws, size_t ws_size,
                              hipStream_t stream) {
  const float* memory = (const float*)d_in[0];
  const int* mlen = (const int*)d_in[1];
  const float* DT = (const float*)d_in[2];
  const float* qW = (const float*)d_in[3];
  const float* memW = (const float*)d_in[4];
  const float* locW = (const float*)d_in[5];
  const float* convW = (const float*)d_in[6];
  const float* wW = (const float*)d_in[7];
  const float* wb = (const float*)d_in[8];
  const float* pW0 = (const float*)d_in[9];
  const float* pW1 = (const float*)d_in[10];
  const float* Wih1 = (const float*)d_in[11];
  const float* Whh1 = (const float*)d_in[12];
  const float* bih1 = (const float*)d_in[13];
  const float* bhh1 = (const float*)d_in[14];
  const float* Wih2 = (const float*)d_in[15];
  const float* Whh2 = (const float*)d_in[16];
  const float* bih2 = (const float*)d_in[17];
  const float* bhh2 = (const float*)d_in[18];
  const float* projW = (const float*)d_in[19];
  const float* gateW = (const float*)d_in[20];
  const float* gateB = (const float*)d_in[21];
  (void)in_sizes; (void)n_in; (void)out_size; (void)d_ws; (void)ws_size;

  float* out_mel = (float*)d_out;
  float* out_gate = out_mel + (size_t)BB * MEL * TDEC;
  float* out_al = out_gate + (size_t)BB * TDEC;

  k_mega<<<NWG, 256, 0, stream>>>(memory, mlen, DT, qW, memW, locW, convW, wW,
                                  wb, pW0, pW1, Wih1, Whh1, bih1, bhh1, Wih2,
                                  Whh2, bih2, bhh2, projW, gateW, gateB,
                                  out_mel, out_gate, out_al);
}

// Round 8
// 541204.102 us; speedup vs baseline: 4.0255x; 1.2342x over previous
//
#include <hip/hip_runtime.h>
#include <hip/hip_bf16.h>

#define BB 64          // batch
#define TENC 512
#define ENCD 512
#define TDEC 600
#define MEL 80
#define RNN 1024
#define ATT 128
#define CC 32
#define KSZ 31
#define PADC 15
#define PRE 256
#define NWG 512
#define FSTR 32        // flag padding: 128 B

// ---- all scratch in __device__ globals ----
__device__ float g_dall[(size_t)TDEC * BB * PRE];   // prenet out, 39.3 MB
__device__ float g_pm[(size_t)BB * TENC * ATT];     // processed_memory, 16.8 MB
__device__ float g_part[16][BB][4096];              // split-K partials, 16.8 MB
__device__ float g_h1[2][BB * RNN];
__device__ float g_c1[BB * RNN];
__device__ float g_h2[2][BB * RNN];
__device__ float g_c2[BB * RNN];
__device__ float g_ctx[BB * ENCD];
__device__ float g_cum[BB * TENC];
__device__ float g_ebuf[BB * TENC];
__device__ float g_pq[BB * ATT];                    // h1 @ qW, once per step

// ---- flag-array grid barrier ----
__device__ unsigned g_flags[NWG * FSTR];   // one padded line per WG
__device__ unsigned g_gen2[FSTR];          // generation word (own line)
__device__ unsigned g_epoch_base;          // carries epoch across launches

// Arrival: each WG release-stores epoch to its own flag line (no RMW, no
// serialization). WG0's threads sweep all 512 flags with RELAXED loads (no
// invalidate per poll), one ACQUIRE joins all release chains, then WG0
// release-publishes g_gen2. Others RELAXED-poll g_gen2 + one ACQUIRE.
__device__ __forceinline__ void grid_sync(unsigned epoch, int wg, int tid) {
  __syncthreads();
  if (tid == 0)
    __hip_atomic_store(&g_flags[wg * FSTR], epoch, __ATOMIC_RELEASE,
                       __HIP_MEMORY_SCOPE_AGENT);
  if (wg == 0) {
    int guard = 0;
    while (__hip_atomic_load(&g_flags[tid * FSTR], __ATOMIC_RELAXED,
                             __HIP_MEMORY_SCOPE_AGENT) < epoch) {
      __builtin_amdgcn_s_sleep(2);
      if (++guard > (1 << 18)) break;
    }
    guard = 0;
    while (__hip_atomic_load(&g_flags[(tid + 256) * FSTR], __ATOMIC_RELAXED,
                             __HIP_MEMORY_SCOPE_AGENT) < epoch) {
      __builtin_amdgcn_s_sleep(2);
      if (++guard > (1 << 18)) break;
    }
    __syncthreads();
    if (tid == 0) {
      (void)__hip_atomic_load(&g_flags[0], __ATOMIC_ACQUIRE,
                              __HIP_MEMORY_SCOPE_AGENT);
      __hip_atomic_store(&g_gen2[0], epoch, __ATOMIC_RELEASE,
                         __HIP_MEMORY_SCOPE_AGENT);
    }
  } else if (tid == 0) {
    int guard = 0;
    while (__hip_atomic_load(&g_gen2[0], __ATOMIC_RELAXED,
                             __HIP_MEMORY_SCOPE_AGENT) < epoch) {
      __builtin_amdgcn_s_sleep(8);
      if (++guard > (1 << 18)) break;
    }
    (void)__hip_atomic_load(&g_gen2[0], __ATOMIC_ACQUIRE,
                            __HIP_MEMORY_SCOPE_AGENT);
  }
  __syncthreads();
}

union SMem {
  struct { float Al[64][68]; float Wl[64][68]; } gemm;                  // 34.8 KB
  struct { float xl[8 * 80]; float hl[8 * 256]; } prenet;               // 10.8 KB
  struct { float ml[8 * 512]; } pm;                                     // 16 KB
  struct { float h1l[RNN]; float pqp[ATT]; } pq;                        // 4.5 KB
  struct {
    float cumext[TENC + 2 * PADC]; float pql[ATT];
    float cWl[CC * KSZ]; float lWl[CC * ATT]; float wl[ATT];
  } en;                                                                 // 23.5 KB
  struct { float pl[TENC]; float red[8]; float part[256]; } sm;         // 3.1 KB
  struct { float dh[RNN + ENCD]; } proj;                                // 6 KB
};

__device__ __forceinline__ float fast_tanh(float x) {
  x = fminf(15.f, fmaxf(-15.f, x));
  float e = __expf(2.f * x);
  return __fdividef(e - 1.f, e + 1.f);
}
__device__ __forceinline__ float fast_sig(float x) {
  x = fminf(30.f, fmaxf(-30.f, x));
  return __fdividef(1.f, 1.f + __expf(-x));
}

// ---------------- prenet job (one (b, t-chunk of 8)) ----------------
__device__ __forceinline__ void prenet_job(SMem& s, int j, int tid,
    const float* __restrict__ DT, const float* __restrict__ W0,
    const float* __restrict__ W1) {
  int b = j / 75, ch = j % 75, t0 = ch * 8;
  for (int i = tid; i < 8 * 80; i += 256) {
    int tt = i / 80, m = i % 80, t = t0 + tt;
    s.prenet.xl[i] = (t == 0) ? 0.f : DT[(size_t)b * (MEL * TDEC) + m * TDEC + (t - 1)];
  }
  __syncthreads();
  {
    float acc[8] = {0, 0, 0, 0, 0, 0, 0, 0};
    for (int m = 0; m < 80; ++m) {
      float w = W0[m * 256 + tid];
#pragma unroll
      for (int tt = 0; tt < 8; ++tt) acc[tt] += s.prenet.xl[tt * 80 + m] * w;
    }
    __syncthreads();
#pragma unroll
    for (int tt = 0; tt < 8; ++tt) s.prenet.hl[tt * 256 + tid] = fmaxf(acc[tt], 0.f);
  }
  __syncthreads();
  {
    float acc[8] = {0, 0, 0, 0, 0, 0, 0, 0};
    for (int jj = 0; jj < 256; ++jj) {
      float w = W1[jj * 256 + tid];
#pragma unroll
      for (int tt = 0; tt < 8; ++tt) acc[tt] += s.prenet.hl[tt * 256 + jj] * w;
    }
#pragma unroll
    for (int tt = 0; tt < 8; ++tt)
      g_dall[((size_t)(t0 + tt) * BB + b) * 256 + tid] = fmaxf(acc[tt], 0.f);
  }
}

// ---------------- processed_memory job (one (b, t-chunk of 8)) -------------
__device__ __forceinline__ void pm_job(SMem& s, int j, int tid,
    const float* __restrict__ mem, const float* __restrict__ mW) {
  int b = j >> 6, t0 = (j & 63) * 8;
  for (int i = tid; i < 8 * 512; i += 256) {
    int tt = i >> 9, d = i & 511;
    s.pm.ml[i] = mem[((size_t)b * TENC + t0 + tt) * ENCD + d];
  }
  __syncthreads();
  int a = tid & 127, th = tid >> 7;
  float acc[4] = {0, 0, 0, 0};
  for (int d = 0; d < 512; ++d) {
    float w = mW[d * 128 + a];
#pragma unroll
    for (int q = 0; q < 4; ++q) acc[q] += s.pm.ml[(th * 4 + q) * 512 + d] * w;
  }
#pragma unroll
  for (int q = 0; q < 4; ++q)
    g_pm[((size_t)b * TENC + t0 + th * 4 + q) * 128 + a] = acc[q];
}

// ---------------- split-K gates GEMM job ----------------
template <int PHASE>
__device__ __forceinline__ void gemm_job(SMem& s, int tid, int nt, int slot,
    int k0, int ksl, int t, const float* __restrict__ Wih,
    const float* __restrict__ Whh, const float* __restrict__ h1p,
    const float* __restrict__ h1n, const float* __restrict__ h2p) {
  constexpr int Kih = (PHASE == 1) ? 768 : 1536;
  const int n0 = nt * 64;
  const int rowq = tid & 15;
  const int colq = tid >> 4;
  float acc[4][4] = {};
  for (int kb = 0; kb < ksl; kb += 64) {
#pragma unroll
    for (int i = 0; i < 16; ++i) {
      int e = i * 256 + tid;
      int kk = e & 63, bb = e >> 6;
      int kg = k0 + kb + kk;
      float v;
      if (PHASE == 1) {
        if (kg < 256) v = g_dall[(size_t)t * BB * PRE + bb * PRE + kg];
        else if (kg < 768) v = g_ctx[bb * ENCD + (kg - 256)];
        else v = h1p[bb * RNN + (kg - 768)];
      } else {
        if (kg < 1024) v = h1n[bb * RNN + kg];
        else if (kg < 1536) v = g_ctx[bb * ENCD + (kg - 1024)];
        else v = h2p[bb * RNN + (kg - 1536)];
      }
      s.gemm.Al[kk][bb] = v;
    }
#pragma unroll
    for (int i = 0; i < 4; ++i) {
      int e = i * 256 + tid;
      int c4 = e & 15, kk = e >> 4;
      int kg = k0 + kb + kk;
      const float* src = (kg < Kih)
                             ? (Wih + (size_t)kg * 4096 + n0 + c4 * 4)
                             : (Whh + (size_t)(kg - Kih) * 4096 + n0 + c4 * 4);
      *(float4*)&s.gemm.Wl[kk][c4 * 4] = *(const float4*)src;
    }
    __syncthreads();
#pragma unroll 8
    for (int kk = 0; kk < 64; ++kk) {
      float4 a4 = *(float4*)&s.gemm.Al[kk][rowq * 4];
      float4 w4 = *(float4*)&s.gemm.Wl[kk][colq * 4];
      float av[4] = {a4.x, a4.y, a4.z, a4.w};
      float wv[4] = {w4.x, w4.y, w4.z, w4.w};
#pragma unroll
      for (int ii = 0; ii < 4; ++ii)
#pragma unroll
        for (int jj = 0; jj < 4; ++jj) acc[ii][jj] += av[ii] * wv[jj];
    }
    __syncthreads();
  }
#pragma unroll
  for (int ii = 0; ii < 4; ++ii) {
    float4 o = {acc[ii][0], acc[ii][1], acc[ii][2], acc[ii][3]};
    *(float4*)&g_part[slot][4 * rowq + ii][n0 + colq * 4] = o;
  }
}

// ---------------- split-K reduce + LSTM pointwise (jobs 0..255) ------------
__device__ __forceinline__ void reduce_lstm_job(int wg, int tid, int first,
    int cnt, const float* __restrict__ bih, const float* __restrict__ bhh,
    float* __restrict__ c_st, float* __restrict__ h_out) {
  const int idx = wg * 256 + tid;
  const int b = idx >> 10;
  const int hcol = idx & 1023;
  float gi = 0.f, gf = 0.f, gg = 0.f, go = 0.f;
  for (int ks = first; ks < first + cnt; ++ks) {
    const float* p = &g_part[ks][b][0];
    gi += p[hcol];
    gf += p[1024 + hcol];
    gg += p[2048 + hcol];
    go += p[3072 + hcol];
  }
  gi += bih[hcol] + bhh[hcol];
  gf += bih[1024 + hcol] + bhh[1024 + hcol];
  gg += bih[2048 + hcol] + bhh[2048 + hcol];
  go += bih[3072 + hcol] + bhh[3072 + hcol];
  float c_old = c_st[idx];
  float cn = fast_sig(gf) * c_old + fast_sig(gi) * fast_tanh(gg);
  c_st[idx] = cn;
  h_out[idx] = fast_sig(go) * fast_tanh(cn);
}

// ---------------- pq = h1 @ qW (jobs 0..63: one per b) ----------------
__device__ __forceinline__ void pq_job(SMem& s, int b, int tid,
    const float* __restrict__ h1, const float* __restrict__ qW) {
  for (int i = tid; i < RNN; i += 256) s.pq.h1l[i] = h1[b * RNN + i];
  __syncthreads();
  int a = tid & 127, kh = tid >> 7;
  float acc = 0.f;
  for (int k = kh * 512; k < kh * 512 + 512; ++k)
    acc += s.pq.h1l[k] * qW[k * ATT + a];
  if (kh) s.pq.pqp[a] = acc;
  __syncthreads();
  if (!kh) g_pq[b * ATT + a] = acc + s.pq.pqp[a];
}

// ---------------- attention energies (jobs 0..127: b x half-T) -------------
__device__ __forceinline__ void energies_job(SMem& s, int wg, int tid,
    const float* __restrict__ convW, const float* __restrict__ locW,
    const float* __restrict__ wW, const float* __restrict__ wb,
    const int* __restrict__ mlen) {
  const int b = wg >> 1;
  const int t0 = (wg & 1) * 256;
  for (int i = tid; i < TENC; i += 256) s.en.cumext[PADC + i] = g_cum[b * TENC + i];
  if (tid < PADC) { s.en.cumext[tid] = 0.f; s.en.cumext[TENC + PADC + tid] = 0.f; }
  for (int i = tid; i < CC * KSZ; i += 256) s.en.cWl[i] = convW[i];
  for (int i = tid; i < CC * ATT; i += 256) s.en.lWl[i] = locW[i];
  if (tid < ATT) { s.en.wl[tid] = wW[tid]; s.en.pql[tid] = g_pq[b * ATT + tid]; }
  __syncthreads();
  const int t = t0 + tid;
  float win[KSZ];
#pragma unroll
  for (int k = 0; k < KSZ; ++k) win[k] = s.en.cumext[t0 + tid + k];
  float lc[CC];
#pragma unroll
  for (int c = 0; c < CC; ++c) {
    float v = 0.f;
#pragma unroll
    for (int k = 0; k < KSZ; ++k) v += win[k] * s.en.cWl[c * KSZ + k];
    lc[c] = v;
  }
  const float* pmrow = g_pm + ((size_t)b * TENC + t) * ATT;
  float e = 0.f;
  for (int a = 0; a < ATT; ++a) {
    float v = s.en.pql[a] + pmrow[a];
#pragma unroll
    for (int c = 0; c < CC; ++c) v += lc[c] * s.en.lWl[c * ATT + a];
    e += s.en.wl[a] * fast_tanh(v);
  }
  int len = mlen[b];
  g_ebuf[b * TENC + t] = (t >= len) ? -1e9f : (e + wb[0]);
}

// ---------------- softmax + ctx + cum + alignment (jobs 0..255) ------------
__device__ __forceinline__ void softmax_job(SMem& s, int wg, int tid,
    const float* __restrict__ memory, float* __restrict__ out_al, int t_step) {
  const int b = wg >> 2;
  const int q = wg & 3;
  float e0 = g_ebuf[b * TENC + tid], e1 = g_ebuf[b * TENC + 256 + tid];
  float m = fmaxf(e0, e1);
#pragma unroll
  for (int o = 32; o > 0; o >>= 1) m = fmaxf(m, __shfl_xor(m, o, 64));
  if ((tid & 63) == 0) s.sm.red[tid >> 6] = m;
  __syncthreads();
  float M = fmaxf(fmaxf(s.sm.red[0], s.sm.red[1]), fmaxf(s.sm.red[2], s.sm.red[3]));
  float p0 = __expf(e0 - M), p1 = __expf(e1 - M);
  s.sm.pl[tid] = p0;
  s.sm.pl[tid + 256] = p1;
  float sum = p0 + p1;
#pragma unroll
  for (int o = 32; o > 0; o >>= 1) sum += __shfl_xor(sum, o, 64);
  if ((tid & 63) == 0) s.sm.red[4 + (tid >> 6)] = sum;
  __syncthreads();
  float S = s.sm.red[4] + s.sm.red[5] + s.sm.red[6] + s.sm.red[7];
  float invS = __fdividef(1.f, S);
  if (q == 0) {
#pragma unroll
    for (int r = 0; r < 2; ++r) {
      int i = tid + r * 256;
      float av = s.sm.pl[i] * invS;
      out_al[(size_t)b * (TDEC * TENC) + (size_t)t_step * TENC + i] = av;
      g_cum[b * TENC + i] += av;
    }
  }
  const int dl = tid & 127, th = tid >> 7;
  const int d = q * 128 + dl;
  const float* mb = memory + (size_t)b * TENC * ENCD;
  float a0 = 0.f;
  for (int tt = th * 256; tt < th * 256 + 256; ++tt)
    a0 += s.sm.pl[tt] * mb[(size_t)tt * ENCD + d];
  s.sm.part[tid] = a0;
  __syncthreads();
  if (tid < 128)
    g_ctx[b * ENCD + q * 128 + tid] = (s.sm.part[tid] + s.sm.part[128 + tid]) * invS;
}

// ---------------- projection + gate (jobs 0..63: b) ----------------
__device__ __forceinline__ void proj_job(SMem& s, int b, int tid,
    const float* __restrict__ h2, const float* __restrict__ projW,
    const float* __restrict__ gateW, const float* __restrict__ gateB,
    float* __restrict__ out_mel, float* __restrict__ out_gate, int t_step) {
  for (int i = tid; i < RNN; i += 256) s.proj.dh[i] = h2[b * RNN + i];
  for (int i = tid; i < ENCD; i += 256) s.proj.dh[RNN + i] = g_ctx[b * ENCD + i];
  __syncthreads();
  if (tid < MEL) {
    float v = 0.f;
    for (int k = 0; k < RNN + ENCD; ++k) v += s.proj.dh[k] * projW[k * MEL + tid];
    out_mel[(size_t)b * (MEL * TDEC) + tid * TDEC + t_step] = v;
  } else if (tid == MEL) {
    float v = gateB[0];
    for (int k = 0; k < RNN + ENCD; ++k) v += s.proj.dh[k] * gateW[k];
    out_gate[b * TDEC + t_step] = v;
  }
}

// ---------------- the persistent mega-kernel ----------------
// 6 barriers/step:
//  PA: gemm1 [256]            || reduce2(t-1)+lstm2 [256]
//  PB: reduce1+lstm1 [256]    || proj(t-1) [64]
//  PC: pq [64]                || gemm2 h2p-slices [256]
//  PD: energies [128]         || gemm2 h1n-slices [256]
//  PE: softmax+ctx [256]
//  PF: gemm2 ctx-slices [256]
__global__ __launch_bounds__(256, 2) void k_mega(
    const float* __restrict__ memory, const int* __restrict__ mlen,
    const float* __restrict__ DT, const float* __restrict__ qW,
    const float* __restrict__ memW, const float* __restrict__ locW,
    const float* __restrict__ convW, const float* __restrict__ wW,
    const float* __restrict__ wb, const float* __restrict__ pW0,
    const float* __restrict__ pW1, const float* __restrict__ Wih1,
    const float* __restrict__ Whh1, const float* __restrict__ bih1,
    const float* __restrict__ bhh1, const float* __restrict__ Wih2,
    const float* __restrict__ Whh2, const float* __restrict__ bih2,
    const float* __restrict__ bhh2, const float* __restrict__ projW,
    const float* __restrict__ gateW, const float* __restrict__ gateB,
    float* __restrict__ out_mel, float* __restrict__ out_gate,
    float* __restrict__ out_al) {
  __shared__ SMem s;
  const int wg = blockIdx.x;
  const int tid = threadIdx.x;
  const int gid = wg * 256 + tid;
  const unsigned base = __hip_atomic_load(&g_epoch_base, __ATOMIC_RELAXED,
                                          __HIP_MEMORY_SCOPE_AGENT);
  unsigned ep = base;

  // ---- pre-phase: init state + prenet + pm ----
  {
    float* z1 = (float*)g_h1;
    float* z2 = (float*)g_h2;
    for (int i = gid; i < 2 * BB * RNN; i += NWG * 256) { z1[i] = 0.f; z2[i] = 0.f; }
    for (int i = gid; i < BB * RNN; i += NWG * 256) { g_c1[i] = 0.f; g_c2[i] = 0.f; }
    for (int i = gid; i < BB * ENCD; i += NWG * 256) g_ctx[i] = 0.f;
    for (int i = gid; i < BB * TENC; i += NWG * 256) g_cum[i] = 0.f;
  }
  for (int j = wg; j < 64 * 75; j += NWG) {
    prenet_job(s, j, tid, DT, pW0, pW1);
    __syncthreads();
  }
  for (int j = wg; j < 64 * 64; j += NWG) {
    pm_job(s, j, tid, memory, memW);
    __syncthreads();
  }
  grid_sync(++ep, wg, tid);

  // ---- 600 decoder steps ----
#pragma unroll 1
  for (int t = 0; t < TDEC; ++t) {
    const int pp = t & 1;
    const float* h1p = g_h1[pp];
    float* h1n = g_h1[1 - pp];
    const float* h2p = g_h2[pp];   // h2(t-1), written below in PA

    // PA: gemm1 || reduce2(t-1)
    if (wg < 256) {
      gemm_job<1>(s, tid, wg & 63, wg >> 6, (wg >> 6) * 448, 448, t,
                  Wih1, Whh1, h1p, nullptr, nullptr);
    } else if (t > 0) {
      reduce_lstm_job(wg - 256, tid, 4, 12, bih2, bhh2, g_c2, g_h2[pp]);
    }
    grid_sync(++ep, wg, tid);

    // PB: reduce1+lstm1 -> h1n || proj(t-1)
    if (wg < 256) {
      reduce_lstm_job(wg, tid, 0, 4, bih1, bhh1, g_c1, h1n);
    } else if (wg < 320 && t > 0) {
      proj_job(s, wg - 256, tid, h2p, projW, gateW, gateB, out_mel, out_gate, t - 1);
    }
    grid_sync(++ep, wg, tid);

    // PC: pq(h1n) || gemm2 h2p-slices (K 1536..2560)
    if (wg < 64) {
      pq_job(s, wg, tid, h1n, qW);
    } else if (wg < 320) {
      int w = wg - 64;
      gemm_job<2>(s, tid, w & 63, 4 + (w >> 6), 1536 + (w >> 6) * 256, 256, t,
                  Wih2, Whh2, nullptr, h1n, h2p);
    }
    grid_sync(++ep, wg, tid);

    // PD: energies || gemm2 h1n-slices (K 0..1024)
    if (wg < 128) {
      energies_job(s, wg, tid, convW, locW, wW, wb, mlen);
    } else if (wg < 384) {
      int w = wg - 128;
      gemm_job<2>(s, tid, w & 63, 8 + (w >> 6), (w >> 6) * 256, 256, t,
                  Wih2, Whh2, nullptr, h1n, h2p);
    }
    grid_sync(++ep, wg, tid);

    // PE: softmax + ctx
    if (wg < 256) softmax_job(s, wg, tid, memory, out_al, t);
    grid_sync(++ep, wg, tid);

    // PF: gemm2 ctx-slices (K 1024..1536)
    if (wg < 256) {
      gemm_job<2>(s, tid, wg & 63, 12 + (wg >> 6), 1024 + (wg >> 6) * 128, 128, t,
                  Wih2, Whh2, nullptr, h1n, h2p);
    }
    grid_sync(++ep, wg, tid);
  }

  // tail: reduce2(599) -> g_h2[0], then proj(599)
  if (wg < 256) reduce_lstm_job(wg, tid, 4, 12, bih2, bhh2, g_c2, g_h2[0]);
  grid_sync(++ep, wg, tid);
  if (wg < 64) proj_job(s, wg, tid, g_h2[0], projW, gateW, gateB, out_mel, out_gate, TDEC - 1);
  if (wg == 0 && tid == 0)
    __hip_atomic_store(&g_epoch_base, ep, __ATOMIC_RELEASE, __HIP_MEMORY_SCOPE_AGENT);
}

extern "C" void kernel_launch(void* const* d_in, const int* in_sizes, int n_in,
                              void* d_out, int out_size, void* d_ws, size_t ws_size,
                              hipStream_t stream) {
  const float* memory = (const float*)d_in[0];
  const int* mlen = (const int*)d_in[1];
  const float* DT = (const float*)d_in[2];
  const float* qW = (const float*)d_in[3];
  const float* memW = (const float*)d_in[4];
  const float* locW = (const float*)d_in[5];
  const float* convW = (const float*)d_in[6];
  const float* wW = (const float*)d_in[7];
  const float* wb = (const float*)d_in[8];
  const float* pW0 = (const float*)d_in[9];
  const float* pW1 = (const float*)d_in[10];
  const float* Wih1 = (const float*)d_in[11];
  const float* Whh1 = (const float*)d_in[12];
  const float* bih1 = (const float*)d_in[13];
  const float* bhh1 = (const float*)d_in[14];
  const float* Wih2 = (const float*)d_in[15];
  const float* Whh2 = (const float*)d_in[16];
  const float* bih2 = (const float*)d_in[17];
  const float* bhh2 = (const float*)d_in[18];
  const float* projW = (const float*)d_in[19];
  const float* gateW = (const float*)d_in[20];
  const float* gateB = (const float*)d_in[21];
  (void)in_sizes; (void)n_in; (void)out_size; (void)d_ws; (void)ws_size;

  float* out_mel = (float*)d_out;
  float* out_gate = out_mel + (size_t)BB * MEL * TDEC;
  float* out_al = out_gate + (size_t)BB * TDEC;

  k_mega<<<NWG, 256, 0, stream>>>(memory, mlen, DT, qW, memW, locW, convW, wW,
                                  wb, pW0, pW1, Wih1, Whh1, bih1, bhh1, Wih2,
                                  Whh2, bih2, bhh2, projW, gateW, gateB,
                                  out_mel, out_gate, out_al);
}

// Round 9
// 458841.357 us; speedup vs baseline: 4.7481x; 1.1795x over previous
//
#include <hip/hip_runtime.h>
#include <hip/hip_bf16.h>

#define BB 64          // batch
#define TENC 512
#define ENCD 512
#define TDEC 600
#define MEL 80
#define RNN 1024
#define ATT 128
#define CC 32
#define KSZ 31
#define PADC 15
#define PRE 256
#define NWG 512
#define FSTR 32        // flag padding: 128 B

// ---- all scratch in __device__ globals ----
__device__ float g_dall[(size_t)TDEC * BB * PRE];   // prenet out, 39.3 MB (RO in loop)
__device__ float g_pm[(size_t)BB * TENC * ATT];     // processed_memory (RO in loop)
__device__ float g_part[16][BB][4096];              // split-K partials (coherent)
__device__ float g_h1[2][BB * RNN];                 // (coherent)
__device__ float g_c1[BB * RNN];                    // private per reduce-WG (cached)
__device__ float g_h2[2][BB * RNN];                 // (coherent)
__device__ float g_c2[BB * RNN];                    // private per reduce-WG (cached)
__device__ float g_ctx[BB * ENCD];                  // (coherent)
__device__ float g_cum[BB * TENC];                  // (coherent)
__device__ float g_ebuf[BB * TENC];                 // (coherent)
__device__ float g_pq[BB * ATT];                    // (coherent)

// ---- flag-array grid barrier ----
__device__ unsigned g_flags[NWG * FSTR];   // one padded line per WG
__device__ unsigned g_gen2[FSTR];          // generation word (own line)
__device__ unsigned g_epoch_base;          // carries epoch across launches

// coherent (agent-scope, RELAXED) access helpers: read/write the coherent
// point directly; never invalidate or write back L2 -> read-only data stays
// cached across barriers.
__device__ __forceinline__ float cload(const float* p) {
  return __hip_atomic_load(p, __ATOMIC_RELAXED, __HIP_MEMORY_SCOPE_AGENT);
}
__device__ __forceinline__ void cstore(float* p, float v) {
  __hip_atomic_store(p, v, __ATOMIC_RELAXED, __HIP_MEMORY_SCOPE_AGENT);
}
__device__ __forceinline__ void fence_vm() {
  asm volatile("s_waitcnt vmcnt(0)" ::: "memory");
}

// LIGHT barrier: all-RELAXED flag protocol. Producer ordering comes from
// s_waitcnt vmcnt(0) (all prior coherent stores ack'd at the coherent point)
// before the flag store. No acquire/release -> no cache invalidation.
__device__ __forceinline__ void grid_sync(unsigned epoch, int wg, int tid) {
  __syncthreads();
  fence_vm();
  if (tid == 0)
    __hip_atomic_store(&g_flags[wg * FSTR], epoch, __ATOMIC_RELAXED,
                       __HIP_MEMORY_SCOPE_AGENT);
  if (wg == 0) {
    int guard = 0;
    while (__hip_atomic_load(&g_flags[tid * FSTR], __ATOMIC_RELAXED,
                             __HIP_MEMORY_SCOPE_AGENT) < epoch) {
      __builtin_amdgcn_s_sleep(2);
      if (++guard > (1 << 20)) break;
    }
    guard = 0;
    while (__hip_atomic_load(&g_flags[(tid + 256) * FSTR], __ATOMIC_RELAXED,
                             __HIP_MEMORY_SCOPE_AGENT) < epoch) {
      __builtin_amdgcn_s_sleep(2);
      if (++guard > (1 << 20)) break;
    }
    __syncthreads();
    if (tid == 0)
      __hip_atomic_store(&g_gen2[0], epoch, __ATOMIC_RELAXED,
                         __HIP_MEMORY_SCOPE_AGENT);
  } else if (tid == 0) {
    int guard = 0;
    while (__hip_atomic_load(&g_gen2[0], __ATOMIC_RELAXED,
                             __HIP_MEMORY_SCOPE_AGENT) < epoch) {
      __builtin_amdgcn_s_sleep(8);
      if (++guard > (1 << 20)) break;
    }
  }
  asm volatile("" ::: "memory");
  __syncthreads();
}

// HEAVY barrier (once, after pre-phase): release arrival (flushes dirty L2 so
// normally-written dall/pm/zeros reach the coherent point) + acquire exit.
__device__ __forceinline__ void grid_sync_full(unsigned epoch, int wg, int tid) {
  __syncthreads();
  if (tid == 0)
    __hip_atomic_store(&g_flags[wg * FSTR], epoch, __ATOMIC_RELEASE,
                       __HIP_MEMORY_SCOPE_AGENT);
  if (wg == 0) {
    int guard = 0;
    while (__hip_atomic_load(&g_flags[tid * FSTR], __ATOMIC_RELAXED,
                             __HIP_MEMORY_SCOPE_AGENT) < epoch) {
      __builtin_amdgcn_s_sleep(2);
      if (++guard > (1 << 20)) break;
    }
    guard = 0;
    while (__hip_atomic_load(&g_flags[(tid + 256) * FSTR], __ATOMIC_RELAXED,
                             __HIP_MEMORY_SCOPE_AGENT) < epoch) {
      __builtin_amdgcn_s_sleep(2);
      if (++guard > (1 << 20)) break;
    }
    __syncthreads();
    if (tid == 0) {
      (void)__hip_atomic_load(&g_flags[0], __ATOMIC_ACQUIRE,
                              __HIP_MEMORY_SCOPE_AGENT);
      __hip_atomic_store(&g_gen2[0], epoch, __ATOMIC_RELEASE,
                         __HIP_MEMORY_SCOPE_AGENT);
    }
  } else if (tid == 0) {
    int guard = 0;
    while (__hip_atomic_load(&g_gen2[0], __ATOMIC_RELAXED,
                             __HIP_MEMORY_SCOPE_AGENT) < epoch) {
      __builtin_amdgcn_s_sleep(8);
      if (++guard > (1 << 20)) break;
    }
    (void)__hip_atomic_load(&g_gen2[0], __ATOMIC_ACQUIRE,
                            __HIP_MEMORY_SCOPE_AGENT);
  }
  __syncthreads();
}

union SMem {
  struct { float Al[64][68]; float Wl[64][68]; } gemm;                  // 34.8 KB
  struct { float xl[8 * 80]; float hl[8 * 256]; } prenet;               // 10.8 KB
  struct { float ml[8 * 512]; } pm;                                     // 16 KB
  struct { float h1l[RNN]; float pqp[ATT]; } pq;                        // 4.5 KB
  struct {
    float cumext[TENC + 2 * PADC]; float pql[ATT];
    float cWl[CC * KSZ]; float lWl[CC * ATT]; float wl[ATT];
  } en;                                                                 // 23.5 KB
  struct { float pl[TENC]; float red[8]; float part[256]; } sm;         // 3.1 KB
  struct { float dh[RNN + ENCD]; } proj;                                // 6 KB
};

__device__ __forceinline__ float fast_tanh(float x) {
  x = fminf(15.f, fmaxf(-15.f, x));
  float e = __expf(2.f * x);
  return __fdividef(e - 1.f, e + 1.f);
}
__device__ __forceinline__ float fast_sig(float x) {
  x = fminf(30.f, fmaxf(-30.f, x));
  return __fdividef(1.f, 1.f + __expf(-x));
}

// ---------------- prenet job (pre-phase; normal stores) ----------------
__device__ __forceinline__ void prenet_job(SMem& s, int j, int tid,
    const float* __restrict__ DT, const float* __restrict__ W0,
    const float* __restrict__ W1) {
  int b = j / 75, ch = j % 75, t0 = ch * 8;
  for (int i = tid; i < 8 * 80; i += 256) {
    int tt = i / 80, m = i % 80, t = t0 + tt;
    s.prenet.xl[i] = (t == 0) ? 0.f : DT[(size_t)b * (MEL * TDEC) + m * TDEC + (t - 1)];
  }
  __syncthreads();
  {
    float acc[8] = {0, 0, 0, 0, 0, 0, 0, 0};
    for (int m = 0; m < 80; ++m) {
      float w = W0[m * 256 + tid];
#pragma unroll
      for (int tt = 0; tt < 8; ++tt) acc[tt] += s.prenet.xl[tt * 80 + m] * w;
    }
    __syncthreads();
#pragma unroll
    for (int tt = 0; tt < 8; ++tt) s.prenet.hl[tt * 256 + tid] = fmaxf(acc[tt], 0.f);
  }
  __syncthreads();
  {
    float acc[8] = {0, 0, 0, 0, 0, 0, 0, 0};
    for (int jj = 0; jj < 256; ++jj) {
      float w = W1[jj * 256 + tid];
#pragma unroll
      for (int tt = 0; tt < 8; ++tt) acc[tt] += s.prenet.hl[tt * 256 + jj] * w;
    }
#pragma unroll
    for (int tt = 0; tt < 8; ++tt)
      g_dall[((size_t)(t0 + tt) * BB + b) * 256 + tid] = fmaxf(acc[tt], 0.f);
  }
}

// ---------------- processed_memory job (pre-phase) ----------------
__device__ __forceinline__ void pm_job(SMem& s, int j, int tid,
    const float* __restrict__ mem, const float* __restrict__ mW) {
  int b = j >> 6, t0 = (j & 63) * 8;
  for (int i = tid; i < 8 * 512; i += 256) {
    int tt = i >> 9, d = i & 511;
    s.pm.ml[i] = mem[((size_t)b * TENC + t0 + tt) * ENCD + d];
  }
  __syncthreads();
  int a = tid & 127, th = tid >> 7;
  float acc[4] = {0, 0, 0, 0};
  for (int d = 0; d < 512; ++d) {
    float w = mW[d * 128 + a];
#pragma unroll
    for (int q = 0; q < 4; ++q) acc[q] += s.pm.ml[(th * 4 + q) * 512 + d] * w;
  }
#pragma unroll
  for (int q = 0; q < 4; ++q)
    g_pm[((size_t)b * TENC + t0 + th * 4 + q) * 128 + a] = acc[q];
}

// ---------------- split-K gates GEMM job ----------------
// A-sources: g_dall cached (RO); ctx/h coherent. W cached (RO).
template <int PHASE>
__device__ __forceinline__ void gemm_job(SMem& s, int tid, int nt, int slot,
    int k0, int ksl, int t, const float* __restrict__ Wih,
    const float* __restrict__ Whh, const float* __restrict__ h1p,
    const float* __restrict__ h1n, const float* __restrict__ h2p) {
  constexpr int Kih = (PHASE == 1) ? 768 : 1536;
  const int n0 = nt * 64;
  const int rowq = tid & 15;
  const int colq = tid >> 4;
  float acc[4][4] = {};
  for (int kb = 0; kb < ksl; kb += 64) {
#pragma unroll
    for (int i = 0; i < 16; ++i) {
      int e = i * 256 + tid;
      int kk = e & 63, bb = e >> 6;
      int kg = k0 + kb + kk;
      float v;
      if (PHASE == 1) {
        if (kg < 256) v = g_dall[(size_t)t * BB * PRE + bb * PRE + kg];
        else if (kg < 768) v = cload(&g_ctx[bb * ENCD + (kg - 256)]);
        else v = cload(&h1p[bb * RNN + (kg - 768)]);
      } else {
        if (kg < 1024) v = cload(&h1n[bb * RNN + kg]);
        else if (kg < 1536) v = cload(&g_ctx[bb * ENCD + (kg - 1024)]);
        else v = cload(&h2p[bb * RNN + (kg - 1536)]);
      }
      s.gemm.Al[kk][bb] = v;
    }
#pragma unroll
    for (int i = 0; i < 4; ++i) {
      int e = i * 256 + tid;
      int c4 = e & 15, kk = e >> 4;
      int kg = k0 + kb + kk;
      const float* src = (kg < Kih)
                             ? (Wih + (size_t)kg * 4096 + n0 + c4 * 4)
                             : (Whh + (size_t)(kg - Kih) * 4096 + n0 + c4 * 4);
      *(float4*)&s.gemm.Wl[kk][c4 * 4] = *(const float4*)src;
    }
    __syncthreads();
#pragma unroll 8
    for (int kk = 0; kk < 64; ++kk) {
      float4 a4 = *(float4*)&s.gemm.Al[kk][rowq * 4];
      float4 w4 = *(float4*)&s.gemm.Wl[kk][colq * 4];
      float av[4] = {a4.x, a4.y, a4.z, a4.w};
      float wv[4] = {w4.x, w4.y, w4.z, w4.w};
#pragma unroll
      for (int ii = 0; ii < 4; ++ii)
#pragma unroll
        for (int jj = 0; jj < 4; ++jj) acc[ii][jj] += av[ii] * wv[jj];
    }
    __syncthreads();
  }
#pragma unroll
  for (int ii = 0; ii < 4; ++ii) {
#pragma unroll
    for (int jj = 0; jj < 4; ++jj)
      cstore(&g_part[slot][4 * rowq + ii][n0 + colq * 4 + jj], acc[ii][jj]);
  }
}

// ---------------- split-K reduce + LSTM pointwise (jobs 0..255) ------------
__device__ __forceinline__ void reduce_lstm_job(int wg, int tid, int first,
    int cnt, const float* __restrict__ bih, const float* __restrict__ bhh,
    float* __restrict__ c_st, float* __restrict__ h_out) {
  const int idx = wg * 256 + tid;
  const int b = idx >> 10;
  const int hcol = idx & 1023;
  float gi = 0.f, gf = 0.f, gg = 0.f, go = 0.f;
  for (int ks = first; ks < first + cnt; ++ks) {
    const float* p = &g_part[ks][b][0];
    gi += cload(&p[hcol]);
    gf += cload(&p[1024 + hcol]);
    gg += cload(&p[2048 + hcol]);
    go += cload(&p[3072 + hcol]);
  }
  gi += bih[hcol] + bhh[hcol];
  gf += bih[1024 + hcol] + bhh[1024 + hcol];
  gg += bih[2048 + hcol] + bhh[2048 + hcol];
  go += bih[3072 + hcol] + bhh[3072 + hcol];
  // c is only ever touched by THIS WG (same idx every step): keep it coherent
  // anyway (cheap, 1 elem) to avoid any stale-line corner.
  float c_old = cload(&c_st[idx]);
  float cn = fast_sig(gf) * c_old + fast_sig(gi) * fast_tanh(gg);
  cstore(&c_st[idx], cn);
  cstore(&h_out[idx], fast_sig(go) * fast_tanh(cn));
}

// ---------------- pq = h1 @ qW (jobs 0..63: one per b) ----------------
__device__ __forceinline__ void pq_job(SMem& s, int b, int tid,
    const float* __restrict__ h1, const float* __restrict__ qW) {
  for (int i = tid; i < RNN; i += 256) s.pq.h1l[i] = cload(&h1[b * RNN + i]);
  __syncthreads();
  int a = tid & 127, kh = tid >> 7;
  float acc = 0.f;
  for (int k = kh * 512; k < kh * 512 + 512; ++k)
    acc += s.pq.h1l[k] * qW[k * ATT + a];
  if (kh) s.pq.pqp[a] = acc;
  __syncthreads();
  if (!kh) cstore(&g_pq[b * ATT + a], acc + s.pq.pqp[a]);
}

// ---------------- attention energies (jobs 0..127: b x half-T) -------------
__device__ __forceinline__ void energies_job(SMem& s, int wg, int tid,
    const float* __restrict__ convW, const float* __restrict__ locW,
    const float* __restrict__ wW, const float* __restrict__ wb,
    const int* __restrict__ mlen) {
  const int b = wg >> 1;
  const int t0 = (wg & 1) * 256;
  for (int i = tid; i < TENC; i += 256)
    s.en.cumext[PADC + i] = cload(&g_cum[b * TENC + i]);
  if (tid < PADC) { s.en.cumext[tid] = 0.f; s.en.cumext[TENC + PADC + tid] = 0.f; }
  for (int i = tid; i < CC * KSZ; i += 256) s.en.cWl[i] = convW[i];
  for (int i = tid; i < CC * ATT; i += 256) s.en.lWl[i] = locW[i];
  if (tid < ATT) { s.en.wl[tid] = wW[tid]; s.en.pql[tid] = cload(&g_pq[b * ATT + tid]); }
  __syncthreads();
  const int t = t0 + tid;
  float win[KSZ];
#pragma unroll
  for (int k = 0; k < KSZ; ++k) win[k] = s.en.cumext[t0 + tid + k];
  float lc[CC];
#pragma unroll
  for (int c = 0; c < CC; ++c) {
    float v = 0.f;
#pragma unroll
    for (int k = 0; k < KSZ; ++k) v += win[k] * s.en.cWl[c * KSZ + k];
    lc[c] = v;
  }
  const float* pmrow = g_pm + ((size_t)b * TENC + t) * ATT;
  float e = 0.f;
  for (int a = 0; a < ATT; ++a) {
    float v = s.en.pql[a] + pmrow[a];
#pragma unroll
    for (int c = 0; c < CC; ++c) v += lc[c] * s.en.lWl[c * ATT + a];
    e += s.en.wl[a] * fast_tanh(v);
  }
  int len = mlen[b];
  cstore(&g_ebuf[b * TENC + t], (t >= len) ? -1e9f : (e + wb[0]));
}

// ---------------- softmax + ctx + cum + alignment (jobs 0..255) ------------
__device__ __forceinline__ void softmax_job(SMem& s, int wg, int tid,
    const float* __restrict__ memory, float* __restrict__ out_al, int t_step) {
  const int b = wg >> 2;
  const int q = wg & 3;
  float e0 = cload(&g_ebuf[b * TENC + tid]);
  float e1 = cload(&g_ebuf[b * TENC + 256 + tid]);
  float m = fmaxf(e0, e1);
#pragma unroll
  for (int o = 32; o > 0; o >>= 1) m = fmaxf(m, __shfl_xor(m, o, 64));
  if ((tid & 63) == 0) s.sm.red[tid >> 6] = m;
  __syncthreads();
  float M = fmaxf(fmaxf(s.sm.red[0], s.sm.red[1]), fmaxf(s.sm.red[2], s.sm.red[3]));
  float p0 = __expf(e0 - M), p1 = __expf(e1 - M);
  s.sm.pl[tid] = p0;
  s.sm.pl[tid + 256] = p1;
  float sum = p0 + p1;
#pragma unroll
  for (int o = 32; o > 0; o >>= 1) sum += __shfl_xor(sum, o, 64);
  if ((tid & 63) == 0) s.sm.red[4 + (tid >> 6)] = sum;
  __syncthreads();
  float S = s.sm.red[4] + s.sm.red[5] + s.sm.red[6] + s.sm.red[7];
  float invS = __fdividef(1.f, S);
  if (q == 0) {
#pragma unroll
    for (int r = 0; r < 2; ++r) {
      int i = tid + r * 256;
      float av = s.sm.pl[i] * invS;
      out_al[(size_t)b * (TDEC * TENC) + (size_t)t_step * TENC + i] = av;
      cstore(&g_cum[b * TENC + i], cload(&g_cum[b * TENC + i]) + av);
    }
  }
  const int dl = tid & 127, th = tid >> 7;
  const int d = q * 128 + dl;
  const float* mb = memory + (size_t)b * TENC * ENCD;
  float a0 = 0.f;
  for (int tt = th * 256; tt < th * 256 + 256; ++tt)
    a0 += s.sm.pl[tt] * mb[(size_t)tt * ENCD + d];
  s.sm.part[tid] = a0;
  __syncthreads();
  if (tid < 128)
    cstore(&g_ctx[b * ENCD + q * 128 + tid],
           (s.sm.part[tid] + s.sm.part[128 + tid]) * invS);
}

// ---------------- projection + gate (jobs 0..63: b) ----------------
__device__ __forceinline__ void proj_job(SMem& s, int b, int tid,
    const float* __restrict__ h2, const float* __restrict__ projW,
    const float* __restrict__ gateW, const float* __restrict__ gateB,
    float* __restrict__ out_mel, float* __restrict__ out_gate, int t_step) {
  for (int i = tid; i < RNN; i += 256) s.proj.dh[i] = cload(&h2[b * RNN + i]);
  for (int i = tid; i < ENCD; i += 256)
    s.proj.dh[RNN + i] = cload(&g_ctx[b * ENCD + i]);
  __syncthreads();
  if (tid < MEL) {
    float v = 0.f;
    for (int k = 0; k < RNN + ENCD; ++k) v += s.proj.dh[k] * projW[k * MEL + tid];
    out_mel[(size_t)b * (MEL * TDEC) + tid * TDEC + t_step] = v;
  } else if (tid == MEL) {
    float v = gateB[0];
    for (int k = 0; k < RNN + ENCD; ++k) v += s.proj.dh[k] * gateW[k];
    out_gate[b * TDEC + t_step] = v;
  }
}

// ---------------- the persistent mega-kernel ----------------
// 6 light barriers/step:
//  PA: gemm1 [256]            || reduce2(t-1)+lstm2 [256]
//  PB: reduce1+lstm1 [256]    || proj(t-1) [64]
//  PC: pq [64]                || gemm2 h2p-slices [256]
//  PD: energies [128]         || gemm2 h1n-slices [256]
//  PE: softmax+ctx [256]
//  PF: gemm2 ctx-slices [256]
__global__ __launch_bounds__(256, 2) void k_mega(
    const float* __restrict__ memory, const int* __restrict__ mlen,
    const float* __restrict__ DT, const float* __restrict__ qW,
    const float* __restrict__ memW, const float* __restrict__ locW,
    const float* __restrict__ convW, const float* __restrict__ wW,
    const float* __restrict__ wb, const float* __restrict__ pW0,
    const float* __restrict__ pW1, const float* __restrict__ Wih1,
    const float* __restrict__ Whh1, const float* __restrict__ bih1,
    const float* __restrict__ bhh1, const float* __restrict__ Wih2,
    const float* __restrict__ Whh2, const float* __restrict__ bih2,
    const float* __restrict__ bhh2, const float* __restrict__ projW,
    const float* __restrict__ gateW, const float* __restrict__ gateB,
    float* __restrict__ out_mel, float* __restrict__ out_gate,
    float* __restrict__ out_al) {
  __shared__ SMem s;
  const int wg = blockIdx.x;
  const int tid = threadIdx.x;
  const int gid = wg * 256 + tid;
  unsigned ep = __hip_atomic_load(&g_epoch_base, __ATOMIC_RELAXED,
                                  __HIP_MEMORY_SCOPE_AGENT);

  // ---- pre-phase: init state + prenet + pm (normal stores) ----
  {
    float* z1 = (float*)g_h1;
    float* z2 = (float*)g_h2;
    for (int i = gid; i < 2 * BB * RNN; i += NWG * 256) { z1[i] = 0.f; z2[i] = 0.f; }
    for (int i = gid; i < BB * RNN; i += NWG * 256) { g_c1[i] = 0.f; g_c2[i] = 0.f; }
    for (int i = gid; i < BB * ENCD; i += NWG * 256) g_ctx[i] = 0.f;
    for (int i = gid; i < BB * TENC; i += NWG * 256) g_cum[i] = 0.f;
  }
  for (int j = wg; j < 64 * 75; j += NWG) {
    prenet_job(s, j, tid, DT, pW0, pW1);
    __syncthreads();
  }
  for (int j = wg; j < 64 * 64; j += NWG) {
    pm_job(s, j, tid, memory, memW);
    __syncthreads();
  }
  grid_sync_full(++ep, wg, tid);   // flush dall/pm/zeros to coherent point

  // ---- 600 decoder steps ----
#pragma unroll 1
  for (int t = 0; t < TDEC; ++t) {
    const int pp = t & 1;
    const float* h1p = g_h1[pp];
    float* h1n = g_h1[1 - pp];
    const float* h2p = g_h2[pp];   // h2(t-1), written below in PA

    // PA: gemm1 || reduce2(t-1)
    if (wg < 256) {
      gemm_job<1>(s, tid, wg & 63, wg >> 6, (wg >> 6) * 448, 448, t,
                  Wih1, Whh1, h1p, nullptr, nullptr);
    } else if (t > 0) {
      reduce_lstm_job(wg - 256, tid, 4, 12, bih2, bhh2, g_c2, g_h2[pp]);
    }
    grid_sync(++ep, wg, tid);

    // PB: reduce1+lstm1 -> h1n || proj(t-1)
    if (wg < 256) {
      reduce_lstm_job(wg, tid, 0, 4, bih1, bhh1, g_c1, h1n);
    } else if (wg < 320 && t > 0) {
      proj_job(s, wg - 256, tid, h2p, projW, gateW, gateB, out_mel, out_gate, t - 1);
    }
    grid_sync(++ep, wg, tid);

    // PC: pq(h1n) || gemm2 h2p-slices (K 1536..2560)
    if (wg < 64) {
      pq_job(s, wg, tid, h1n, qW);
    } else if (wg < 320) {
      int w = wg - 64;
      gemm_job<2>(s, tid, w & 63, 4 + (w >> 6), 1536 + (w >> 6) * 256, 256, t,
                  Wih2, Whh2, nullptr, h1n, h2p);
    }
    grid_sync(++ep, wg, tid);

    // PD: energies || gemm2 h1n-slices (K 0..1024)
    if (wg < 128) {
      energies_job(s, wg, tid, convW, locW, wW, wb, mlen);
    } else if (wg < 384) {
      int w = wg - 128;
      gemm_job<2>(s, tid, w & 63, 8 + (w >> 6), (w >> 6) * 256, 256, t,
                  Wih2, Whh2, nullptr, h1n, h2p);
    }
    grid_sync(++ep, wg, tid);

    // PE: softmax + ctx
    if (wg < 256) softmax_job(s, wg, tid, memory, out_al, t);
    grid_sync(++ep, wg, tid);

    // PF: gemm2 ctx-slices (K 1024..1536)
    if (wg < 256) {
      gemm_job<2>(s, tid, wg & 63, 12 + (wg >> 6), 1024 + (wg >> 6) * 128, 128, t,
                  Wih2, Whh2, nullptr, h1n, h2p);
    }
    grid_sync(++ep, wg, tid);
  }

  // tail: reduce2(599) -> g_h2[0], then proj(599)
  if (wg < 256) reduce_lstm_job(wg, tid, 4, 12, bih2, bhh2, g_c2, g_h2[0]);
  grid_sync(++ep, wg, tid);
  if (wg < 64) proj_job(s, wg, tid, g_h2[0], projW, gateW, gateB, out_mel, out_gate, TDEC - 1);
  if (wg == 0 && tid == 0)
    __hip_atomic_store(&g_epoch_base, ep, __ATOMIC_RELAXED, __HIP_MEMORY_SCOPE_AGENT);
}

extern "C" void kernel_launch(void* const* d_in, const int* in_sizes, int n_in,
                              void* d_out, int out_size, void* d_ws, size_t ws_size,
                              hipStream_t stream) {
  const float* memory = (const float*)d_in[0];
  const int* mlen = (const int*)d_in[1];
  const float* DT = (const float*)d_in[2];
  const float* qW = (const float*)d_in[3];
  const float* memW = (const float*)d_in[4];
  const float* locW = (const float*)d_in[5];
  const float* convW = (const float*)d_in[6];
  const float* wW = (const float*)d_in[7];
  const float* wb = (const float*)d_in[8];
  const float* pW0 = (const float*)d_in[9];
  const float* pW1 = (const float*)d_in[10];
  const float* Wih1 = (const float*)d_in[11];
  const float* Whh1 = (const float*)d_in[12];
  const float* bih1 = (const float*)d_in[13];
  const float* bhh1 = (const float*)d_in[14];
  const float* Wih2 = (const float*)d_in[15];
  const float* Whh2 = (const float*)d_in[16];
  const float* bih2 = (const float*)d_in[17];
  const float* bhh2 = (const float*)d_in[18];
  const float* projW = (const float*)d_in[19];
  const float* gateW = (const float*)d_in[20];
  const float* gateB = (const float*)d_in[21];
  (void)in_sizes; (void)n_in; (void)out_size; (void)d_ws; (void)ws_size;

  float* out_mel = (float*)d_out;
  float* out_gate = out_mel + (size_t)BB * MEL * TDEC;
  float* out_al = out_gate + (size_t)BB * TDEC;

  k_mega<<<NWG, 256, 0, stream>>>(memory, mlen, DT, qW, memW, locW, convW, wW,
                                  wb, pW0, pW1, Wih1, Whh1, bih1, bhh1, Wih2,
                                  Whh2, bih2, bhh2, projW, gateW, gateB,
                                  out_mel, out_gate, out_al);
}

// Round 11
// 424001.465 us; speedup vs baseline: 5.1383x; 1.0822x over previous
//
#include <hip/hip_runtime.h>
#include <hip/hip_bf16.h>

#define BB 64          // batch
#define TENC 512
#define ENCD 512
#define TDEC 600
#define MEL 80
#define RNN 1024
#define ATT 128
#define CC 32
#define KSZ 31
#define PADC 15
#define PRE 256
#define NWG 512
#define FSTR 32        // flag padding: 128 B

// native register vector (NOT HIP float4 -- that's a class and cannot be an
// inline-asm "v" operand)
typedef float f4 __attribute__((ext_vector_type(4)));

// ---- all scratch in __device__ globals; transposed [feature][batch] ----
__device__ __attribute__((aligned(16))) float g_dallT[(size_t)TDEC * PRE * BB]; // [t][k][b]
__device__ __attribute__((aligned(16))) float g_pm[(size_t)BB * TENC * ATT];    // [b][t][a] (RO cached)
__device__ __attribute__((aligned(16))) float g_part[16][4096][BB];             // [slot][col][b]
__device__ __attribute__((aligned(16))) float g_h1T[2][RNN * BB];
__device__ __attribute__((aligned(16))) float g_c1T[RNN * BB];
__device__ __attribute__((aligned(16))) float g_h2T[2][RNN * BB];
__device__ __attribute__((aligned(16))) float g_c2T[RNN * BB];
__device__ __attribute__((aligned(16))) float g_ctxT[ENCD * BB];
__device__ __attribute__((aligned(16))) float g_cum[BB * TENC];
__device__ __attribute__((aligned(16))) float g_ebuf[BB * TENC];
__device__ __attribute__((aligned(16))) float g_pq[BB * ATT];

// ---- flag-array grid barrier ----
__device__ unsigned g_flags[NWG * FSTR];
__device__ unsigned g_gen2[FSTR];
__device__ unsigned g_epoch_base;

// scalar coherent helpers (low-volume paths)
__device__ __forceinline__ float cload(const float* p) {
  return __hip_atomic_load(p, __ATOMIC_RELAXED, __HIP_MEMORY_SCOPE_AGENT);
}
__device__ __forceinline__ void cstore(float* p, float v) {
  __hip_atomic_store(p, v, __ATOMIC_RELAXED, __HIP_MEMORY_SCOPE_AGENT);
}
// wide coherent helpers: dwordx4 with sc0 sc1 (device-coherent, bypasses
// L1/L2, coalesced). Batch of 4 shares one vmcnt wait.
__device__ __forceinline__ void cload4x4(const float* p0, const float* p1,
    const float* p2, const float* p3, f4& a, f4& b, f4& c, f4& d) {
  asm volatile(
      "global_load_dwordx4 %0, %4, off sc0 sc1\n\t"
      "global_load_dwordx4 %1, %5, off sc0 sc1\n\t"
      "global_load_dwordx4 %2, %6, off sc0 sc1\n\t"
      "global_load_dwordx4 %3, %7, off sc0 sc1\n\t"
      "s_waitcnt vmcnt(0)"
      : "=&v"(a), "=&v"(b), "=&v"(c), "=&v"(d)
      : "v"(p0), "v"(p1), "v"(p2), "v"(p3)
      : "memory");
}
__device__ __forceinline__ f4 cload4(const float* p) {
  f4 v;
  asm volatile("global_load_dwordx4 %0, %1, off sc0 sc1\n\ts_waitcnt vmcnt(0)"
               : "=&v"(v) : "v"(p) : "memory");
  return v;
}
__device__ __forceinline__ void cstore4(float* p, f4 v) {
  asm volatile("global_store_dwordx4 %0, %1, off sc0 sc1" :: "v"(p), "v"(v)
               : "memory");
}
__device__ __forceinline__ void fence_vm() {
  asm volatile("s_waitcnt vmcnt(0)" ::: "memory");
}

// LIGHT barrier: all-RELAXED flag protocol; producer ordering via vmcnt(0).
__device__ __forceinline__ void grid_sync(unsigned epoch, int wg, int tid) {
  __syncthreads();
  fence_vm();
  if (tid == 0)
    __hip_atomic_store(&g_flags[wg * FSTR], epoch, __ATOMIC_RELAXED,
                       __HIP_MEMORY_SCOPE_AGENT);
  if (wg == 0) {
    int guard = 0;
    while (__hip_atomic_load(&g_flags[tid * FSTR], __ATOMIC_RELAXED,
                             __HIP_MEMORY_SCOPE_AGENT) < epoch) {
      __builtin_amdgcn_s_sleep(2);
      if (++guard > (1 << 20)) break;
    }
    guard = 0;
    while (__hip_atomic_load(&g_flags[(tid + 256) * FSTR], __ATOMIC_RELAXED,
                             __HIP_MEMORY_SCOPE_AGENT) < epoch) {
      __builtin_amdgcn_s_sleep(2);
      if (++guard > (1 << 20)) break;
    }
    __syncthreads();
    if (tid == 0)
      __hip_atomic_store(&g_gen2[0], epoch, __ATOMIC_RELAXED,
                         __HIP_MEMORY_SCOPE_AGENT);
  } else if (tid == 0) {
    int guard = 0;
    while (__hip_atomic_load(&g_gen2[0], __ATOMIC_RELAXED,
                             __HIP_MEMORY_SCOPE_AGENT) < epoch) {
      __builtin_amdgcn_s_sleep(8);
      if (++guard > (1 << 20)) break;
    }
  }
  asm volatile("" ::: "memory");
  __syncthreads();
}

// HEAVY barrier (once after pre-phase): release flushes dirty L2 (dall/pm).
__device__ __forceinline__ void grid_sync_full(unsigned epoch, int wg, int tid) {
  __syncthreads();
  if (tid == 0)
    __hip_atomic_store(&g_flags[wg * FSTR], epoch, __ATOMIC_RELEASE,
                       __HIP_MEMORY_SCOPE_AGENT);
  if (wg == 0) {
    int guard = 0;
    while (__hip_atomic_load(&g_flags[tid * FSTR], __ATOMIC_RELAXED,
                             __HIP_MEMORY_SCOPE_AGENT) < epoch) {
      __builtin_amdgcn_s_sleep(2);
      if (++guard > (1 << 20)) break;
    }
    guard = 0;
    while (__hip_atomic_load(&g_flags[(tid + 256) * FSTR], __ATOMIC_RELAXED,
                             __HIP_MEMORY_SCOPE_AGENT) < epoch) {
      __builtin_amdgcn_s_sleep(2);
      if (++guard > (1 << 20)) break;
    }
    __syncthreads();
    if (tid == 0) {
      (void)__hip_atomic_load(&g_flags[0], __ATOMIC_ACQUIRE,
                              __HIP_MEMORY_SCOPE_AGENT);
      __hip_atomic_store(&g_gen2[0], epoch, __ATOMIC_RELEASE,
                         __HIP_MEMORY_SCOPE_AGENT);
    }
  } else if (tid == 0) {
    int guard = 0;
    while (__hip_atomic_load(&g_gen2[0], __ATOMIC_RELAXED,
                             __HIP_MEMORY_SCOPE_AGENT) < epoch) {
      __builtin_amdgcn_s_sleep(8);
      if (++guard > (1 << 20)) break;
    }
    (void)__hip_atomic_load(&g_gen2[0], __ATOMIC_ACQUIRE,
                            __HIP_MEMORY_SCOPE_AGENT);
  }
  __syncthreads();
}

union SMem {
  struct { float Al[64][68]; float Wl[64][68]; } gemm;                  // 34.8 KB
  struct { float xl[8 * 80]; float hl[8 * 256]; } prenet;               // 10.8 KB
  struct { float ml[8 * 512]; } pm;                                     // 16 KB
  struct { float h1l[RNN]; float pqp[ATT]; } pq;                        // 4.5 KB
  struct {
    float cumext[TENC + 2 * PADC]; float pql[ATT];
    float cWl[CC * KSZ]; float lWl[CC * ATT]; float wl[ATT];
  } en;                                                                 // 23.5 KB
  struct { float pl[TENC]; float red[8]; float part[256]; } sm;         // 3.1 KB
  struct { float dh[RNN + ENCD]; } proj;                                // 6 KB
};

__device__ __forceinline__ float fast_tanh(float x) {
  x = fminf(15.f, fmaxf(-15.f, x));
  float e = __expf(2.f * x);
  return __fdividef(e - 1.f, e + 1.f);
}
__device__ __forceinline__ float fast_sig(float x) {
  x = fminf(30.f, fmaxf(-30.f, x));
  return __fdividef(1.f, 1.f + __expf(-x));
}

// ---------------- prenet job (pre-phase; normal stores, transposed out) ----
__device__ __forceinline__ void prenet_job(SMem& s, int j, int tid,
    const float* __restrict__ DT, const float* __restrict__ W0,
    const float* __restrict__ W1) {
  int b = j / 75, ch = j % 75, t0 = ch * 8;
  for (int i = tid; i < 8 * 80; i += 256) {
    int tt = i / 80, m = i % 80, t = t0 + tt;
    s.prenet.xl[i] = (t == 0) ? 0.f : DT[(size_t)b * (MEL * TDEC) + m * TDEC + (t - 1)];
  }
  __syncthreads();
  {
    float acc[8] = {0, 0, 0, 0, 0, 0, 0, 0};
    for (int m = 0; m < 80; ++m) {
      float w = W0[m * 256 + tid];
#pragma unroll
      for (int tt = 0; tt < 8; ++tt) acc[tt] += s.prenet.xl[tt * 80 + m] * w;
    }
    __syncthreads();
#pragma unroll
    for (int tt = 0; tt < 8; ++tt) s.prenet.hl[tt * 256 + tid] = fmaxf(acc[tt], 0.f);
  }
  __syncthreads();
  {
    float acc[8] = {0, 0, 0, 0, 0, 0, 0, 0};
    for (int jj = 0; jj < 256; ++jj) {
      float w = W1[jj * 256 + tid];
#pragma unroll
      for (int tt = 0; tt < 8; ++tt) acc[tt] += s.prenet.hl[tt * 256 + jj] * w;
    }
#pragma unroll
    for (int tt = 0; tt < 8; ++tt)
      g_dallT[((size_t)(t0 + tt) * PRE + tid) * BB + b] = fmaxf(acc[tt], 0.f);
  }
}

// ---------------- processed_memory job (pre-phase) ----------------
__device__ __forceinline__ void pm_job(SMem& s, int j, int tid,
    const float* __restrict__ mem, const float* __restrict__ mW) {
  int b = j >> 6, t0 = (j & 63) * 8;
  for (int i = tid; i < 8 * 512; i += 256) {
    int tt = i >> 9, d = i & 511;
    s.pm.ml[i] = mem[((size_t)b * TENC + t0 + tt) * ENCD + d];
  }
  __syncthreads();
  int a = tid & 127, th = tid >> 7;
  float acc[4] = {0, 0, 0, 0};
  for (int d = 0; d < 512; ++d) {
    float w = mW[d * 128 + a];
#pragma unroll
    for (int q = 0; q < 4; ++q) acc[q] += s.pm.ml[(th * 4 + q) * 512 + d] * w;
  }
#pragma unroll
  for (int q = 0; q < 4; ++q)
    g_pm[((size_t)b * TENC + t0 + th * 4 + q) * 128 + a] = acc[q];
}

// ---------------- split-K gates GEMM job (transposed A, f4 coherent) -------
// A regions: [0,R0)->aT0, [R0,R1)->aT1, [R1,K)->aT2, each [feature][64b].
template <int PHASE>
__device__ __forceinline__ void gemm_job(SMem& s, int tid, int nt, int slot,
    int k0, int ksl, const float* __restrict__ Wih,
    const float* __restrict__ Whh, const float* __restrict__ aT0,
    const float* __restrict__ aT1, const float* __restrict__ aT2) {
  constexpr int Kih = (PHASE == 1) ? 768 : 1536;
  constexpr int R0 = (PHASE == 1) ? 256 : 1024;
  constexpr int R1 = (PHASE == 1) ? 768 : 1536;
  const int n0 = nt * 64;
  const int rowq = tid & 15;
  const int colq = tid >> 4;
  float acc[4][4] = {};
  for (int kb = 0; kb < ksl; kb += 64) {
    // A-stage: 4 coherent f4 per thread, [kk][b] layout -> b128 LDS writes
    {
      const float* pp[4];
#pragma unroll
      for (int j = 0; j < 4; ++j) {
        int kk = j * 16 + (tid >> 4);
        int kg = k0 + kb + kk;
        const float* base = (kg < R0) ? aT0 + (size_t)kg * BB
                          : (kg < R1) ? aT1 + (size_t)(kg - R0) * BB
                                      : aT2 + (size_t)(kg - R1) * BB;
        pp[j] = base + (tid & 15) * 4;
      }
      f4 av0, av1, av2, av3;
      cload4x4(pp[0], pp[1], pp[2], pp[3], av0, av1, av2, av3);
      int kb0 = tid >> 4, c4 = (tid & 15) * 4;
      *(f4*)&s.gemm.Al[kb0][c4] = av0;
      *(f4*)&s.gemm.Al[16 + kb0][c4] = av1;
      *(f4*)&s.gemm.Al[32 + kb0][c4] = av2;
      *(f4*)&s.gemm.Al[48 + kb0][c4] = av3;
    }
    // W-stage: normal cached float4
#pragma unroll
    for (int i = 0; i < 4; ++i) {
      int e = i * 256 + tid;
      int c4 = e & 15, kk = e >> 4;
      int kg = k0 + kb + kk;
      const float* src = (kg < Kih)
                             ? (Wih + (size_t)kg * 4096 + n0 + c4 * 4)
                             : (Whh + (size_t)(kg - Kih) * 4096 + n0 + c4 * 4);
      *(f4*)&s.gemm.Wl[kk][c4 * 4] = *(const f4*)src;
    }
    __syncthreads();
#pragma unroll 8
    for (int kk = 0; kk < 64; ++kk) {
      f4 a4 = *(f4*)&s.gemm.Al[kk][rowq * 4];
      f4 w4 = *(f4*)&s.gemm.Wl[kk][colq * 4];
      float av[4] = {a4.x, a4.y, a4.z, a4.w};
      float wv[4] = {w4.x, w4.y, w4.z, w4.w};
#pragma unroll
      for (int ii = 0; ii < 4; ++ii)
#pragma unroll
        for (int jj = 0; jj < 4; ++jj) acc[ii][jj] += av[ii] * wv[jj];
    }
    __syncthreads();
  }
  // partial store: [col][b] f4 over batches
#pragma unroll
  for (int jj = 0; jj < 4; ++jj) {
    f4 o = {acc[0][jj], acc[1][jj], acc[2][jj], acc[3][jj]};
    cstore4(&g_part[slot][n0 + colq * 4 + jj][rowq * 4], o);
  }
}

// ---------------- split-K reduce + LSTM pointwise (64 WGs, f4) -------------
__device__ __forceinline__ void reduce_lstm_job(int wg, int tid, int first,
    int cnt, const float* __restrict__ bih, const float* __restrict__ bhh,
    float* __restrict__ cT, float* __restrict__ hT) {
  const int hcol = wg * 16 + (tid >> 4);
  const int b4 = (tid & 15) * 4;
  f4 G0 = {0, 0, 0, 0}, G1 = {0, 0, 0, 0}, G2 = {0, 0, 0, 0}, G3 = {0, 0, 0, 0};
  for (int ks = first; ks < first + cnt; ++ks) {
    f4 x0, x1, x2, x3;
    cload4x4(&g_part[ks][hcol][b4], &g_part[ks][1024 + hcol][b4],
             &g_part[ks][2048 + hcol][b4], &g_part[ks][3072 + hcol][b4],
             x0, x1, x2, x3);
    G0 += x0; G1 += x1; G2 += x2; G3 += x3;
  }
  const float bi = bih[hcol] + bhh[hcol];
  const float bff = bih[1024 + hcol] + bhh[1024 + hcol];
  const float bg = bih[2048 + hcol] + bhh[2048 + hcol];
  const float bo = bih[3072 + hcol] + bhh[3072 + hcol];
  f4 c_old = cload4(&cT[hcol * BB + b4]);
  f4 cn, hn;
  {
    float c0 = fast_sig(G1.x + bff) * c_old.x + fast_sig(G0.x + bi) * fast_tanh(G2.x + bg);
    float c1 = fast_sig(G1.y + bff) * c_old.y + fast_sig(G0.y + bi) * fast_tanh(G2.y + bg);
    float c2 = fast_sig(G1.z + bff) * c_old.z + fast_sig(G0.z + bi) * fast_tanh(G2.z + bg);
    float c3 = fast_sig(G1.w + bff) * c_old.w + fast_sig(G0.w + bi) * fast_tanh(G2.w + bg);
    cn = {c0, c1, c2, c3};
    hn = {fast_sig(G3.x + bo) * fast_tanh(c0), fast_sig(G3.y + bo) * fast_tanh(c1),
          fast_sig(G3.z + bo) * fast_tanh(c2), fast_sig(G3.w + bo) * fast_tanh(c3)};
  }
  cstore4(&cT[hcol * BB + b4], cn);
  cstore4(&hT[hcol * BB + b4], hn);
}

// ---------------- pq = h1 @ qW (jobs 0..63: one per b) ----------------
__device__ __forceinline__ void pq_job(SMem& s, int b, int tid,
    const float* __restrict__ h1T, const float* __restrict__ qW) {
  for (int i = tid; i < RNN; i += 256) s.pq.h1l[i] = cload(&h1T[i * BB + b]);
  __syncthreads();
  int a = tid & 127, kh = tid >> 7;
  float acc = 0.f;
  for (int k = kh * 512; k < kh * 512 + 512; ++k)
    acc += s.pq.h1l[k] * qW[k * ATT + a];
  if (kh) s.pq.pqp[a] = acc;
  __syncthreads();
  if (!kh) cstore(&g_pq[b * ATT + a], acc + s.pq.pqp[a]);
}

// ---------------- attention energies (jobs 0..127: b x half-T) -------------
__device__ __forceinline__ void energies_job(SMem& s, int wg, int tid,
    const float* __restrict__ convW, const float* __restrict__ locW,
    const float* __restrict__ wW, const float* __restrict__ wb,
    const int* __restrict__ mlen) {
  const int b = wg >> 1;
  const int t0 = (wg & 1) * 256;
  for (int i = tid; i < TENC; i += 256)
    s.en.cumext[PADC + i] = cload(&g_cum[b * TENC + i]);
  if (tid < PADC) { s.en.cumext[tid] = 0.f; s.en.cumext[TENC + PADC + tid] = 0.f; }
  for (int i = tid; i < CC * KSZ; i += 256) s.en.cWl[i] = convW[i];
  for (int i = tid; i < CC * ATT; i += 256) s.en.lWl[i] = locW[i];
  if (tid < ATT) { s.en.wl[tid] = wW[tid]; s.en.pql[tid] = cload(&g_pq[b * ATT + tid]); }
  __syncthreads();
  const int t = t0 + tid;
  float win[KSZ];
#pragma unroll
  for (int k = 0; k < KSZ; ++k) win[k] = s.en.cumext[t0 + tid + k];
  float lc[CC];
#pragma unroll
  for (int c = 0; c < CC; ++c) {
    float v = 0.f;
#pragma unroll
    for (int k = 0; k < KSZ; ++k) v += win[k] * s.en.cWl[c * KSZ + k];
    lc[c] = v;
  }
  const float* pmrow = g_pm + ((size_t)b * TENC + t) * ATT;
  float e = 0.f;
  for (int a = 0; a < ATT; ++a) {
    float v = s.en.pql[a] + pmrow[a];
#pragma unroll
    for (int c = 0; c < CC; ++c) v += lc[c] * s.en.lWl[c * ATT + a];
    e += s.en.wl[a] * fast_tanh(v);
  }
  int len = mlen[b];
  cstore(&g_ebuf[b * TENC + t], (t >= len) ? -1e9f : (e + wb[0]));
}

// ---------------- softmax + ctx + cum + alignment (jobs 0..255) ------------
__device__ __forceinline__ void softmax_job(SMem& s, int wg, int tid,
    const float* __restrict__ memory, float* __restrict__ out_al, int t_step) {
  const int b = wg >> 2;
  const int q = wg & 3;
  float e0 = cload(&g_ebuf[b * TENC + tid]);
  float e1 = cload(&g_ebuf[b * TENC + 256 + tid]);
  float m = fmaxf(e0, e1);
#pragma unroll
  for (int o = 32; o > 0; o >>= 1) m = fmaxf(m, __shfl_xor(m, o, 64));
  if ((tid & 63) == 0) s.sm.red[tid >> 6] = m;
  __syncthreads();
  float M = fmaxf(fmaxf(s.sm.red[0], s.sm.red[1]), fmaxf(s.sm.red[2], s.sm.red[3]));
  float p0 = __expf(e0 - M), p1 = __expf(e1 - M);
  s.sm.pl[tid] = p0;
  s.sm.pl[tid + 256] = p1;
  float sum = p0 + p1;
#pragma unroll
  for (int o = 32; o > 0; o >>= 1) sum += __shfl_xor(sum, o, 64);
  if ((tid & 63) == 0) s.sm.red[4 + (tid >> 6)] = sum;
  __syncthreads();
  float S = s.sm.red[4] + s.sm.red[5] + s.sm.red[6] + s.sm.red[7];
  float invS = __fdividef(1.f, S);
  if (q == 0) {
#pragma unroll
    for (int r = 0; r < 2; ++r) {
      int i = tid + r * 256;
      float av = s.sm.pl[i] * invS;
      out_al[(size_t)b * (TDEC * TENC) + (size_t)t_step * TENC + i] = av;
      cstore(&g_cum[b * TENC + i], cload(&g_cum[b * TENC + i]) + av);
    }
  }
  const int dl = tid & 127, th = tid >> 7;
  const int d = q * 128 + dl;
  const float* mb = memory + (size_t)b * TENC * ENCD;
  float a0 = 0.f;
  for (int tt = th * 256; tt < th * 256 + 256; ++tt)
    a0 += s.sm.pl[tt] * mb[(size_t)tt * ENCD + d];
  s.sm.part[tid] = a0;
  __syncthreads();
  if (tid < 128)
    cstore(&g_ctxT[(q * 128 + tid) * BB + b],
           (s.sm.part[tid] + s.sm.part[128 + tid]) * invS);
}

// ---------------- projection + gate (jobs 0..63: b) ----------------
__device__ __forceinline__ void proj_job(SMem& s, int b, int tid,
    const float* __restrict__ h2T, const float* __restrict__ projW,
    const float* __restrict__ gateW, const float* __restrict__ gateB,
    float* __restrict__ out_mel, float* __restrict__ out_gate, int t_step) {
  for (int i = tid; i < RNN; i += 256) s.proj.dh[i] = cload(&h2T[i * BB + b]);
  for (int i = tid; i < ENCD; i += 256)
    s.proj.dh[RNN + i] = cload(&g_ctxT[i * BB + b]);
  __syncthreads();
  if (tid < MEL) {
    float v = 0.f;
    for (int k = 0; k < RNN + ENCD; ++k) v += s.proj.dh[k] * projW[k * MEL + tid];
    out_mel[(size_t)b * (MEL * TDEC) + tid * TDEC + t_step] = v;
  } else if (tid == MEL) {
    float v = gateB[0];
    for (int k = 0; k < RNN + ENCD; ++k) v += s.proj.dh[k] * gateW[k];
    out_gate[b * TDEC + t_step] = v;
  }
}

// ---------------- the persistent mega-kernel ----------------
// 6 light barriers/step:
//  PA: gemm1 [256]            || reduce2(t-1) [64]
//  PB: reduce1 [64]           || proj(t-1) [64]
//  PC: pq [64]                || gemm2 h2p-slices [256]
//  PD: energies [128]         || gemm2 h1n-slices [256]
//  PE: softmax+ctx [256]
//  PF: gemm2 ctx-slices [256]
__global__ __launch_bounds__(256, 2) void k_mega(
    const float* __restrict__ memory, const int* __restrict__ mlen,
    const float* __restrict__ DT, const float* __restrict__ qW,
    const float* __restrict__ memW, const float* __restrict__ locW,
    const float* __restrict__ convW, const float* __restrict__ wW,
    const float* __restrict__ wb, const float* __restrict__ pW0,
    const float* __restrict__ pW1, const float* __restrict__ Wih1,
    const float* __restrict__ Whh1, const float* __restrict__ bih1,
    const float* __restrict__ bhh1, const float* __restrict__ Wih2,
    const float* __restrict__ Whh2, const float* __restrict__ bih2,
    const float* __restrict__ bhh2, const float* __restrict__ projW,
    const float* __restrict__ gateW, const float* __restrict__ gateB,
    float* __restrict__ out_mel, float* __restrict__ out_gate,
    float* __restrict__ out_al) {
  __shared__ SMem s;
  const int wg = blockIdx.x;
  const int tid = threadIdx.x;
  const int gid = wg * 256 + tid;
  unsigned ep = __hip_atomic_load(&g_epoch_base, __ATOMIC_RELAXED,
                                  __HIP_MEMORY_SCOPE_AGENT);

  // ---- pre-phase: init state + prenet + pm (normal stores) ----
  {
    float* z1 = (float*)g_h1T;
    float* z2 = (float*)g_h2T;
    for (int i = gid; i < 2 * BB * RNN; i += NWG * 256) { z1[i] = 0.f; z2[i] = 0.f; }
    for (int i = gid; i < BB * RNN; i += NWG * 256) { g_c1T[i] = 0.f; g_c2T[i] = 0.f; }
    for (int i = gid; i < BB * ENCD; i += NWG * 256) g_ctxT[i] = 0.f;
    for (int i = gid; i < BB * TENC; i += NWG * 256) g_cum[i] = 0.f;
  }
  for (int j = wg; j < 64 * 75; j += NWG) {
    prenet_job(s, j, tid, DT, pW0, pW1);
    __syncthreads();
  }
  for (int j = wg; j < 64 * 64; j += NWG) {
    pm_job(s, j, tid, memory, memW);
    __syncthreads();
  }
  grid_sync_full(++ep, wg, tid);

  // ---- 600 decoder steps ----
#pragma unroll 1
  for (int t = 0; t < TDEC; ++t) {
    const int pp = t & 1;
    const float* h1pT = g_h1T[pp];
    float* h1nT = g_h1T[1 - pp];
    const float* h2pT = g_h2T[pp];   // h2(t-1), written below in PA
    const float* dallT = g_dallT + (size_t)t * PRE * BB;

    // PA: gemm1 || reduce2(t-1)
    if (wg < 256) {
      gemm_job<1>(s, tid, wg & 63, wg >> 6, (wg >> 6) * 448, 448,
                  Wih1, Whh1, dallT, g_ctxT, h1pT);
    } else if (wg < 320 && t > 0) {
      reduce_lstm_job(wg - 256, tid, 4, 12, bih2, bhh2, g_c2T, g_h2T[pp]);
    }
    grid_sync(++ep, wg, tid);

    // PB: reduce1 -> h1n || proj(t-1)
    if (wg < 64) {
      reduce_lstm_job(wg, tid, 0, 4, bih1, bhh1, g_c1T, h1nT);
    } else if (wg < 128 && t > 0) {
      proj_job(s, wg - 64, tid, h2pT, projW, gateW, gateB, out_mel, out_gate, t - 1);
    }
    grid_sync(++ep, wg, tid);

    // PC: pq(h1n) || gemm2 h2p-slices (K 1536..2560)
    if (wg < 64) {
      pq_job(s, wg, tid, h1nT, qW);
    } else if (wg < 320) {
      int w = wg - 64;
      gemm_job<2>(s, tid, w & 63, 4 + (w >> 6), 1536 + (w >> 6) * 256, 256,
                  Wih2, Whh2, h1nT, g_ctxT, h2pT);
    }
    grid_sync(++ep, wg, tid);

    // PD: energies || gemm2 h1n-slices (K 0..1024)
    if (wg < 128) {
      energies_job(s, wg, tid, convW, locW, wW, wb, mlen);
    } else if (wg < 384) {
      int w = wg - 128;
      gemm_job<2>(s, tid, w & 63, 8 + (w >> 6), (w >> 6) * 256, 256,
                  Wih2, Whh2, h1nT, g_ctxT, h2pT);
    }
    grid_sync(++ep, wg, tid);

    // PE: softmax + ctx
    if (wg < 256) softmax_job(s, wg, tid, memory, out_al, t);
    grid_sync(++ep, wg, tid);

    // PF: gemm2 ctx-slices (K 1024..1536)
    if (wg < 256) {
      gemm_job<2>(s, tid, wg & 63, 12 + (wg >> 6), 1024 + (wg >> 6) * 128, 128,
                  Wih2, Whh2, h1nT, g_ctxT, h2pT);
    }
    grid_sync(++ep, wg, tid);
  }

  // tail: reduce2(599) -> g_h2T[0], then proj(599)
  if (wg < 64) reduce_lstm_job(wg, tid, 4, 12, bih2, bhh2, g_c2T, g_h2T[0]);
  grid_sync(++ep, wg, tid);
  if (wg < 64) proj_job(s, wg, tid, g_h2T[0], projW, gateW, gateB, out_mel, out_gate, TDEC - 1);
  if (wg == 0 && tid == 0)
    __hip_atomic_store(&g_epoch_base, ep, __ATOMIC_RELAXED, __HIP_MEMORY_SCOPE_AGENT);
}

extern "C" void kernel_launch(void* const* d_in, const int* in_sizes, int n_in,
                              void* d_out, int out_size, void* d_ws, size_t ws_size,
                              hipStream_t stream) {
  const float* memory = (const float*)d_in[0];
  const int* mlen = (const int*)d_in[1];
  const float* DT = (const float*)d_in[2];
  const float* qW = (const float*)d_in[3];
  const float* memW = (const float*)d_in[4];
  const float* locW = (const float*)d_in[5];
  const float* convW = (const float*)d_in[6];
  const float* wW = (const float*)d_in[7];
  const float* wb = (const float*)d_in[8];
  const float* pW0 = (const float*)d_in[9];
  const float* pW1 = (const float*)d_in[10];
  const float* Wih1 = (const float*)d_in[11];
  const float* Whh1 = (const float*)d_in[12];
  const float* bih1 = (const float*)d_in[13];
  const float* bhh1 = (const float*)d_in[14];
  const float* Wih2 = (const float*)d_in[15];
  const float* Whh2 = (const float*)d_in[16];
  const float* bih2 = (const float*)d_in[17];
  const float* bhh2 = (const float*)d_in[18];
  const float* projW = (const float*)d_in[19];
  const float* gateW = (const float*)d_in[20];
  const float* gateB = (const float*)d_in[21];
  (void)in_sizes; (void)n_in; (void)out_size; (void)d_ws; (void)ws_size;

  float* out_mel = (float*)d_out;
  float* out_gate = out_mel + (size_t)BB * MEL * TDEC;
  float* out_al = out_gate + (size_t)BB * TDEC;

  k_mega<<<NWG, 256, 0, stream>>>(memory, mlen, DT, qW, memW, locW, convW, wW,
                                  wb, pW0, pW1, Wih1, Whh1, bih1, bhh1, Wih2,
                                  Whh2, bih2, bhh2, projW, gateW, gateB,
                                  out_mel, out_gate, out_al);
}

// Round 12
// 395715.186 us; speedup vs baseline: 5.5056x; 1.0715x over previous
//
#include <hip/hip_runtime.h>
#include <hip/hip_bf16.h>

#define BB 64          // batch
#define TENC 512
#define ENCD 512
#define TDEC 600
#define MEL 80
#define RNN 1024
#define ATT 128
#define CC 32
#define KSZ 31
#define PADC 15
#define PRE 256
#define NWG 512
#define FSTR 32        // flag padding: 128 B

typedef float f4 __attribute__((ext_vector_type(4)));
typedef unsigned int u32x4 __attribute__((ext_vector_type(4)));
typedef unsigned int u32x2 __attribute__((ext_vector_type(2)));
typedef unsigned short u16;
typedef unsigned int uint_;

#define BLO(u) __uint_as_float((u) << 16)
#define BHI(u) __uint_as_float((u) & 0xffff0000u)

// ---- all scratch in __device__ globals; transposed [feature][batch] ----
__device__ __attribute__((aligned(16))) float g_dallT[(size_t)TDEC * PRE * BB]; // [t][k][b] f32
__device__ __attribute__((aligned(16))) float g_pm[(size_t)BB * TENC * ATT];    // f32 (RO cached)
__device__ __attribute__((aligned(16))) u16 g_W1b[(size_t)1792 * 4096];         // bf16 [Wih1|Whh1]
__device__ __attribute__((aligned(16))) u16 g_W2b[(size_t)2560 * 4096];         // bf16 [Wih2|Whh2]
__device__ __attribute__((aligned(16))) float g_part[16][4096][BB];             // [slot][col][b]
__device__ __attribute__((aligned(16))) float g_h1T[2][RNN * BB];
__device__ __attribute__((aligned(16))) float g_c1T[RNN * BB];
__device__ __attribute__((aligned(16))) float g_h2T[2][RNN * BB];
__device__ __attribute__((aligned(16))) float g_c2T[RNN * BB];
__device__ __attribute__((aligned(16))) float g_ctxT[ENCD * BB];
__device__ __attribute__((aligned(16))) float g_cum[BB * TENC];
__device__ __attribute__((aligned(16))) float g_ebuf[BB * TENC];
__device__ __attribute__((aligned(16))) float g_pq[BB * ATT];

// ---- flag-array grid barrier ----
__device__ unsigned g_flags[NWG * FSTR];
__device__ unsigned g_gen2[FSTR];
__device__ unsigned g_epoch_base;

__device__ __forceinline__ u16 f2b(float f) {  // RNE f32 -> bf16
  uint_ x = __float_as_uint(f);
  uint_ r = x + 0x7fffu + ((x >> 16) & 1u);
  return (u16)(r >> 16);
}

// scalar coherent helpers
__device__ __forceinline__ float cload(const float* p) {
  return __hip_atomic_load(p, __ATOMIC_RELAXED, __HIP_MEMORY_SCOPE_AGENT);
}
__device__ __forceinline__ void cstore(float* p, float v) {
  __hip_atomic_store(p, v, __ATOMIC_RELAXED, __HIP_MEMORY_SCOPE_AGENT);
}
// wide coherent helpers: dwordx4 sc0 sc1 (device-coherent, L2-bypass)
__device__ __forceinline__ void cload4x4(const float* p0, const float* p1,
    const float* p2, const float* p3, f4& a, f4& b, f4& c, f4& d) {
  asm volatile(
      "global_load_dwordx4 %0, %4, off sc0 sc1\n\t"
      "global_load_dwordx4 %1, %5, off sc0 sc1\n\t"
      "global_load_dwordx4 %2, %6, off sc0 sc1\n\t"
      "global_load_dwordx4 %3, %7, off sc0 sc1\n\t"
      "s_waitcnt vmcnt(0)"
      : "=&v"(a), "=&v"(b), "=&v"(c), "=&v"(d)
      : "v"(p0), "v"(p1), "v"(p2), "v"(p3)
      : "memory");
}
__device__ __forceinline__ f4 cload4(const float* p) {
  f4 v;
  asm volatile("global_load_dwordx4 %0, %1, off sc0 sc1\n\ts_waitcnt vmcnt(0)"
               : "=&v"(v) : "v"(p) : "memory");
  return v;
}
__device__ __forceinline__ void cstore4(float* p, f4 v) {
  asm volatile("global_store_dwordx4 %0, %1, off sc0 sc1" :: "v"(p), "v"(v)
               : "memory");
}
__device__ __forceinline__ void fence_vm() {
  asm volatile("s_waitcnt vmcnt(0)" ::: "memory");
}

// LIGHT barrier: all-RELAXED flags; producer ordering via vmcnt(0).
__device__ __forceinline__ void grid_sync(unsigned epoch, int wg, int tid) {
  __syncthreads();
  fence_vm();
  if (tid == 0)
    __hip_atomic_store(&g_flags[wg * FSTR], epoch, __ATOMIC_RELAXED,
                       __HIP_MEMORY_SCOPE_AGENT);
  if (wg == 0) {
    int guard = 0;
    while (__hip_atomic_load(&g_flags[tid * FSTR], __ATOMIC_RELAXED,
                             __HIP_MEMORY_SCOPE_AGENT) < epoch) {
      __builtin_amdgcn_s_sleep(2);
      if (++guard > (1 << 20)) break;
    }
    guard = 0;
    while (__hip_atomic_load(&g_flags[(tid + 256) * FSTR], __ATOMIC_RELAXED,
                             __HIP_MEMORY_SCOPE_AGENT) < epoch) {
      __builtin_amdgcn_s_sleep(2);
      if (++guard > (1 << 20)) break;
    }
    __syncthreads();
    if (tid == 0)
      __hip_atomic_store(&g_gen2[0], epoch, __ATOMIC_RELAXED,
                         __HIP_MEMORY_SCOPE_AGENT);
  } else if (tid == 0) {
    int guard = 0;
    while (__hip_atomic_load(&g_gen2[0], __ATOMIC_RELAXED,
                             __HIP_MEMORY_SCOPE_AGENT) < epoch) {
      __builtin_amdgcn_s_sleep(8);
      if (++guard > (1 << 20)) break;
    }
  }
  asm volatile("" ::: "memory");
  __syncthreads();
}

// HEAVY barrier (once after pre-phase): release flushes dirty L2.
__device__ __forceinline__ void grid_sync_full(unsigned epoch, int wg, int tid) {
  __syncthreads();
  if (tid == 0)
    __hip_atomic_store(&g_flags[wg * FSTR], epoch, __ATOMIC_RELEASE,
                       __HIP_MEMORY_SCOPE_AGENT);
  if (wg == 0) {
    int guard = 0;
    while (__hip_atomic_load(&g_flags[tid * FSTR], __ATOMIC_RELAXED,
                             __HIP_MEMORY_SCOPE_AGENT) < epoch) {
      __builtin_amdgcn_s_sleep(2);
      if (++guard > (1 << 20)) break;
    }
    guard = 0;
    while (__hip_atomic_load(&g_flags[(tid + 256) * FSTR], __ATOMIC_RELAXED,
                             __HIP_MEMORY_SCOPE_AGENT) < epoch) {
      __builtin_amdgcn_s_sleep(2);
      if (++guard > (1 << 20)) break;
    }
    __syncthreads();
    if (tid == 0) {
      (void)__hip_atomic_load(&g_flags[0], __ATOMIC_ACQUIRE,
                              __HIP_MEMORY_SCOPE_AGENT);
      __hip_atomic_store(&g_gen2[0], epoch, __ATOMIC_RELEASE,
                         __HIP_MEMORY_SCOPE_AGENT);
    }
  } else if (tid == 0) {
    int guard = 0;
    while (__hip_atomic_load(&g_gen2[0], __ATOMIC_RELAXED,
                             __HIP_MEMORY_SCOPE_AGENT) < epoch) {
      __builtin_amdgcn_s_sleep(8);
      if (++guard > (1 << 20)) break;
    }
    (void)__hip_atomic_load(&g_gen2[0], __ATOMIC_ACQUIRE,
                            __HIP_MEMORY_SCOPE_AGENT);
  }
  __syncthreads();
}

union SMem {
  struct { float Al[64][68]; u16 Wlb[64][136]; } gemm;                  // 34 KB
  struct { float xl[8 * 80]; float hl[8 * 256]; } prenet;               // 10.8 KB
  struct { float ml[8 * 512]; } pm;                                     // 16 KB
  struct { float h1l[RNN]; float pqp[ATT]; } pq;                        // 4.5 KB
  struct {
    float cumext[TENC + 2 * PADC]; float pql[ATT];
    float cWl[CC * KSZ]; float lWl[CC * ATT]; float wl[ATT];
  } en;                                                                 // 23.5 KB
  struct { float pl[TENC]; float red[8]; float part[256]; } sm;         // 3.1 KB
  struct { float dh[RNN + ENCD]; } proj;                                // 6 KB
};

__device__ __forceinline__ float fast_tanh(float x) {
  x = fminf(15.f, fmaxf(-15.f, x));
  float e = __expf(2.f * x);
  return __fdividef(e - 1.f, e + 1.f);
}
__device__ __forceinline__ float fast_sig(float x) {
  x = fminf(30.f, fmaxf(-30.f, x));
  return __fdividef(1.f, 1.f + __expf(-x));
}

// ---------------- prenet job (pre-phase) ----------------
__device__ __forceinline__ void prenet_job(SMem& s, int j, int tid,
    const float* __restrict__ DT, const float* __restrict__ W0,
    const float* __restrict__ W1) {
  int b = j / 75, ch = j % 75, t0 = ch * 8;
  for (int i = tid; i < 8 * 80; i += 256) {
    int tt = i / 80, m = i % 80, t = t0 + tt;
    s.prenet.xl[i] = (t == 0) ? 0.f : DT[(size_t)b * (MEL * TDEC) + m * TDEC + (t - 1)];
  }
  __syncthreads();
  {
    float acc[8] = {0, 0, 0, 0, 0, 0, 0, 0};
    for (int m = 0; m < 80; ++m) {
      float w = W0[m * 256 + tid];
#pragma unroll
      for (int tt = 0; tt < 8; ++tt) acc[tt] += s.prenet.xl[tt * 80 + m] * w;
    }
    __syncthreads();
#pragma unroll
    for (int tt = 0; tt < 8; ++tt) s.prenet.hl[tt * 256 + tid] = fmaxf(acc[tt], 0.f);
  }
  __syncthreads();
  {
    float acc[8] = {0, 0, 0, 0, 0, 0, 0, 0};
    for (int jj = 0; jj < 256; ++jj) {
      float w = W1[jj * 256 + tid];
#pragma unroll
      for (int tt = 0; tt < 8; ++tt) acc[tt] += s.prenet.hl[tt * 256 + jj] * w;
    }
#pragma unroll
    for (int tt = 0; tt < 8; ++tt)
      g_dallT[((size_t)(t0 + tt) * PRE + tid) * BB + b] = fmaxf(acc[tt], 0.f);
  }
}

// ---------------- processed_memory job (pre-phase) ----------------
__device__ __forceinline__ void pm_job(SMem& s, int j, int tid,
    const float* __restrict__ mem, const float* __restrict__ mW) {
  int b = j >> 6, t0 = (j & 63) * 8;
  for (int i = tid; i < 8 * 512; i += 256) {
    int tt = i >> 9, d = i & 511;
    s.pm.ml[i] = mem[((size_t)b * TENC + t0 + tt) * ENCD + d];
  }
  __syncthreads();
  int a = tid & 127, th = tid >> 7;
  float acc[4] = {0, 0, 0, 0};
  for (int d = 0; d < 512; ++d) {
    float w = mW[d * 128 + a];
#pragma unroll
    for (int q = 0; q < 4; ++q) acc[q] += s.pm.ml[(th * 4 + q) * 512 + d] * w;
  }
#pragma unroll
  for (int q = 0; q < 4; ++q)
    g_pm[((size_t)b * TENC + t0 + th * 4 + q) * 128 + a] = acc[q];
}

// ---------------- split-K gates GEMM job ----------------
// Tile: 64 b x 128 cols (nt in 0..31). W is combined bf16 [K][4096].
// A regions (f32, coherent): [0,R0)->aT0, [R0,R1)->aT1, [R1,K)->aT2.
template <int PHASE>
__device__ __forceinline__ void gemm_job(SMem& s, int tid, int nt, int slot,
    int k0, int ksl, const u16* __restrict__ Wb,
    const float* __restrict__ aT0, const float* __restrict__ aT1,
    const float* __restrict__ aT2) {
  constexpr int R0 = (PHASE == 1) ? 256 : 1024;
  constexpr int R1 = (PHASE == 1) ? 768 : 1536;
  const int n0 = nt * 128;
  const int bq = tid & 15;   // batches bq*4..+4
  const int cq = tid >> 4;   // cols cq*8..+8
  float acc[4][8] = {};
  for (int kb = 0; kb < ksl; kb += 64) {
    // A-stage: 4 coherent f4 per thread -> Al[kk][b]
    {
      const float* pp[4];
#pragma unroll
      for (int j = 0; j < 4; ++j) {
        int kk = j * 16 + (tid >> 4);
        int kg = k0 + kb + kk;
        const float* base = (kg < R0) ? aT0 + (size_t)kg * BB
                          : (kg < R1) ? aT1 + (size_t)(kg - R0) * BB
                                      : aT2 + (size_t)(kg - R1) * BB;
        pp[j] = base + (tid & 15) * 4;
      }
      f4 av0, av1, av2, av3;
      cload4x4(pp[0], pp[1], pp[2], pp[3], av0, av1, av2, av3);
      int kb0 = tid >> 4, c4 = (tid & 15) * 4;
      *(f4*)&s.gemm.Al[kb0][c4] = av0;
      *(f4*)&s.gemm.Al[16 + kb0][c4] = av1;
      *(f4*)&s.gemm.Al[32 + kb0][c4] = av2;
      *(f4*)&s.gemm.Al[48 + kb0][c4] = av3;
    }
    // W-stage: 64 kk x 128 cols bf16 = 1024 x 16B units, 4 per thread
#pragma unroll
    for (int i = 0; i < 4; ++i) {
      int e = i * 256 + tid;
      int kk = e >> 4, c8 = e & 15;
      const u16* src = Wb + (size_t)(k0 + kb + kk) * 4096 + n0 + c8 * 8;
      *(u32x4*)&s.gemm.Wlb[kk][c8 * 8] = *(const u32x4*)src;
    }
    __syncthreads();
#pragma unroll 4
    for (int kk = 0; kk < 64; ++kk) {
      f4 a4 = *(f4*)&s.gemm.Al[kk][bq * 4];
      u32x4 wv = *(u32x4*)&s.gemm.Wlb[kk][cq * 8];
      float w[8] = {BLO(wv.x), BHI(wv.x), BLO(wv.y), BHI(wv.y),
                    BLO(wv.z), BHI(wv.z), BLO(wv.w), BHI(wv.w)};
      float a[4] = {a4.x, a4.y, a4.z, a4.w};
#pragma unroll
      for (int ii = 0; ii < 4; ++ii)
#pragma unroll
        for (int jj = 0; jj < 8; ++jj) acc[ii][jj] += a[ii] * w[jj];
    }
    __syncthreads();
  }
#pragma unroll
  for (int jj = 0; jj < 8; ++jj) {
    f4 o = {acc[0][jj], acc[1][jj], acc[2][jj], acc[3][jj]};
    cstore4(&g_part[slot][n0 + cq * 8 + jj][bq * 4], o);
  }
}

// ---------------- split-K reduce + LSTM pointwise (64 WGs, f4) -------------
__device__ __forceinline__ void reduce_lstm_job(int wg, int tid, int first,
    int cnt, const float* __restrict__ bih, const float* __restrict__ bhh,
    float* __restrict__ cT, float* __restrict__ hT) {
  const int hcol = wg * 16 + (tid >> 4);
  const int b4 = (tid & 15) * 4;
  f4 G0 = {0, 0, 0, 0}, G1 = {0, 0, 0, 0}, G2 = {0, 0, 0, 0}, G3 = {0, 0, 0, 0};
  for (int ks = first; ks < first + cnt; ++ks) {
    f4 x0, x1, x2, x3;
    cload4x4(&g_part[ks][hcol][b4], &g_part[ks][1024 + hcol][b4],
             &g_part[ks][2048 + hcol][b4], &g_part[ks][3072 + hcol][b4],
             x0, x1, x2, x3);
    G0 += x0; G1 += x1; G2 += x2; G3 += x3;
  }
  const float bi = bih[hcol] + bhh[hcol];
  const float bff = bih[1024 + hcol] + bhh[1024 + hcol];
  const float bg = bih[2048 + hcol] + bhh[2048 + hcol];
  const float bo = bih[3072 + hcol] + bhh[3072 + hcol];
  f4 c_old = cload4(&cT[hcol * BB + b4]);
  f4 cn, hn;
  {
    float c0 = fast_sig(G1.x + bff) * c_old.x + fast_sig(G0.x + bi) * fast_tanh(G2.x + bg);
    float c1 = fast_sig(G1.y + bff) * c_old.y + fast_sig(G0.y + bi) * fast_tanh(G2.y + bg);
    float c2 = fast_sig(G1.z + bff) * c_old.z + fast_sig(G0.z + bi) * fast_tanh(G2.z + bg);
    float c3 = fast_sig(G1.w + bff) * c_old.w + fast_sig(G0.w + bi) * fast_tanh(G2.w + bg);
    cn = {c0, c1, c2, c3};
    hn = {fast_sig(G3.x + bo) * fast_tanh(c0), fast_sig(G3.y + bo) * fast_tanh(c1),
          fast_sig(G3.z + bo) * fast_tanh(c2), fast_sig(G3.w + bo) * fast_tanh(c3)};
  }
  cstore4(&cT[hcol * BB + b4], cn);
  cstore4(&hT[hcol * BB + b4], hn);
}

// ---------------- pq = h1 @ qW (jobs 0..63: one per b) ----------------
__device__ __forceinline__ void pq_job(SMem& s, int b, int tid,
    const float* __restrict__ h1T, const float* __restrict__ qW) {
  for (int i = tid; i < RNN; i += 256) s.pq.h1l[i] = cload(&h1T[i * BB + b]);
  __syncthreads();
  int a = tid & 127, kh = tid >> 7;
  float acc = 0.f;
  for (int k = kh * 512; k < kh * 512 + 512; ++k)
    acc += s.pq.h1l[k] * qW[k * ATT + a];
  if (kh) s.pq.pqp[a] = acc;
  __syncthreads();
  if (!kh) cstore(&g_pq[b * ATT + a], acc + s.pq.pqp[a]);
}

// ---------------- attention energies (jobs 0..127) ----------------
__device__ __forceinline__ void energies_job(SMem& s, int wg, int tid,
    const float* __restrict__ convW, const float* __restrict__ locW,
    const float* __restrict__ wW, const float* __restrict__ wb,
    const int* __restrict__ mlen) {
  const int b = wg >> 1;
  const int t0 = (wg & 1) * 256;
  for (int i = tid; i < TENC; i += 256)
    s.en.cumext[PADC + i] = cload(&g_cum[b * TENC + i]);
  if (tid < PADC) { s.en.cumext[tid] = 0.f; s.en.cumext[TENC + PADC + tid] = 0.f; }
  for (int i = tid; i < CC * KSZ; i += 256) s.en.cWl[i] = convW[i];
  for (int i = tid; i < CC * ATT; i += 256) s.en.lWl[i] = locW[i];
  if (tid < ATT) { s.en.wl[tid] = wW[tid]; s.en.pql[tid] = cload(&g_pq[b * ATT + tid]); }
  __syncthreads();
  const int t = t0 + tid;
  float win[KSZ];
#pragma unroll
  for (int k = 0; k < KSZ; ++k) win[k] = s.en.cumext[t0 + tid + k];
  float lc[CC];
#pragma unroll
  for (int c = 0; c < CC; ++c) {
    float v = 0.f;
#pragma unroll
    for (int k = 0; k < KSZ; ++k) v += win[k] * s.en.cWl[c * KSZ + k];
    lc[c] = v;
  }
  const float* pmrow = g_pm + ((size_t)b * TENC + t) * ATT;
  float e = 0.f;
  for (int a = 0; a < ATT; ++a) {
    float v = s.en.pql[a] + pmrow[a];
#pragma unroll
    for (int c = 0; c < CC; ++c) v += lc[c] * s.en.lWl[c * ATT + a];
    e += s.en.wl[a] * fast_tanh(v);
  }
  int len = mlen[b];
  cstore(&g_ebuf[b * TENC + t], (t >= len) ? -1e9f : (e + wb[0]));
}

// ---------------- softmax + ctx + cum + alignment (jobs 0..255) ------------
__device__ __forceinline__ void softmax_job(SMem& s, int wg, int tid,
    const float* __restrict__ memory, float* __restrict__ out_al, int t_step) {
  const int b = wg >> 2;
  const int q = wg & 3;
  float e0 = cload(&g_ebuf[b * TENC + tid]);
  float e1 = cload(&g_ebuf[b * TENC + 256 + tid]);
  float m = fmaxf(e0, e1);
#pragma unroll
  for (int o = 32; o > 0; o >>= 1) m = fmaxf(m, __shfl_xor(m, o, 64));
  if ((tid & 63) == 0) s.sm.red[tid >> 6] = m;
  __syncthreads();
  float M = fmaxf(fmaxf(s.sm.red[0], s.sm.red[1]), fmaxf(s.sm.red[2], s.sm.red[3]));
  float p0 = __expf(e0 - M), p1 = __expf(e1 - M);
  s.sm.pl[tid] = p0;
  s.sm.pl[tid + 256] = p1;
  float sum = p0 + p1;
#pragma unroll
  for (int o = 32; o > 0; o >>= 1) sum += __shfl_xor(sum, o, 64);
  if ((tid & 63) == 0) s.sm.red[4 + (tid >> 6)] = sum;
  __syncthreads();
  float S = s.sm.red[4] + s.sm.red[5] + s.sm.red[6] + s.sm.red[7];
  float invS = __fdividef(1.f, S);
  if (q == 0) {
#pragma unroll
    for (int r = 0; r < 2; ++r) {
      int i = tid + r * 256;
      float av = s.sm.pl[i] * invS;
      out_al[(size_t)b * (TDEC * TENC) + (size_t)t_step * TENC + i] = av;
      cstore(&g_cum[b * TENC + i], cload(&g_cum[b * TENC + i]) + av);
    }
  }
  const int dl = tid & 127, th = tid >> 7;
  const int d = q * 128 + dl;
  const float* mb = memory + (size_t)b * TENC * ENCD;
  float a0 = 0.f;
  for (int tt = th * 256; tt < th * 256 + 256; ++tt)
    a0 += s.sm.pl[tt] * mb[(size_t)tt * ENCD + d];
  s.sm.part[tid] = a0;
  __syncthreads();
  if (tid < 128)
    cstore(&g_ctxT[(q * 128 + tid) * BB + b],
           (s.sm.part[tid] + s.sm.part[128 + tid]) * invS);
}

// ---------------- projection + gate (jobs 0..63: b) ----------------
__device__ __forceinline__ void proj_job(SMem& s, int b, int tid,
    const float* __restrict__ h2T, const float* __restrict__ projW,
    const float* __restrict__ gateW, const float* __restrict__ gateB,
    float* __restrict__ out_mel, float* __restrict__ out_gate, int t_step) {
  for (int i = tid; i < RNN; i += 256) s.proj.dh[i] = cload(&h2T[i * BB + b]);
  for (int i = tid; i < ENCD; i += 256)
    s.proj.dh[RNN + i] = cload(&g_ctxT[i * BB + b]);
  __syncthreads();
  if (tid < MEL) {
    float v = 0.f;
    for (int k = 0; k < RNN + ENCD; ++k) v += s.proj.dh[k] * projW[k * MEL + tid];
    out_mel[(size_t)b * (MEL * TDEC) + tid * TDEC + t_step] = v;
  } else if (tid == MEL) {
    float v = gateB[0];
    for (int k = 0; k < RNN + ENCD; ++k) v += s.proj.dh[k] * gateW[k];
    out_gate[b * TDEC + t_step] = v;
  }
}

// ---------------- the persistent mega-kernel ----------------
// 6 light barriers/step:
//  PA: gemm1 [128]            || reduce2(t-1) [64]
//  PB: reduce1 [64]           || proj(t-1) [64]
//  PC: pq [64]                || gemm2 h2p-slices [128]
//  PD: energies [128]         || gemm2 h1n-slices [128]
//  PE: softmax+ctx [256]
//  PF: gemm2 ctx-slices [128]
__global__ __launch_bounds__(256, 2) void k_mega(
    const float* __restrict__ memory, const int* __restrict__ mlen,
    const float* __restrict__ DT, const float* __restrict__ qW,
    const float* __restrict__ memW, const float* __restrict__ locW,
    const float* __restrict__ convW, const float* __restrict__ wW,
    const float* __restrict__ wb, const float* __restrict__ pW0,
    const float* __restrict__ pW1, const float* __restrict__ Wih1,
    const float* __restrict__ Whh1, const float* __restrict__ bih1,
    const float* __restrict__ bhh1, const float* __restrict__ Wih2,
    const float* __restrict__ Whh2, const float* __restrict__ bih2,
    const float* __restrict__ bhh2, const float* __restrict__ projW,
    const float* __restrict__ gateW, const float* __restrict__ gateB,
    float* __restrict__ out_mel, float* __restrict__ out_gate,
    float* __restrict__ out_al) {
  __shared__ SMem s;
  const int wg = blockIdx.x;
  const int tid = threadIdx.x;
  const int gid = wg * 256 + tid;
  unsigned ep = __hip_atomic_load(&g_epoch_base, __ATOMIC_RELAXED,
                                  __HIP_MEMORY_SCOPE_AGENT);

  // ---- pre-phase: init state + weight bf16 conversion + prenet + pm ----
  {
    float* z1 = (float*)g_h1T;
    float* z2 = (float*)g_h2T;
    for (int i = gid; i < 2 * BB * RNN; i += NWG * 256) { z1[i] = 0.f; z2[i] = 0.f; }
    for (int i = gid; i < BB * RNN; i += NWG * 256) { g_c1T[i] = 0.f; g_c2T[i] = 0.f; }
    for (int i = gid; i < BB * ENCD; i += NWG * 256) g_ctxT[i] = 0.f;
    for (int i = gid; i < BB * TENC; i += NWG * 256) g_cum[i] = 0.f;
  }
  {
    // W1b: [0,768)=Wih1, [768,1792)=Whh1
    const size_t n4 = (size_t)1792 * 4096 / 4;
    for (size_t e = gid; e < n4; e += (size_t)NWG * 256) {
      size_t idx = e * 4;
      int k = (int)(idx >> 12), n = (int)(idx & 4095);
      const float* src = (k < 768) ? Wih1 + (size_t)k * 4096 + n
                                   : Whh1 + (size_t)(k - 768) * 4096 + n;
      f4 v = *(const f4*)src;
      u32x2 p;
      p.x = (uint_)f2b(v.x) | ((uint_)f2b(v.y) << 16);
      p.y = (uint_)f2b(v.z) | ((uint_)f2b(v.w) << 16);
      *(u32x2*)&g_W1b[idx] = p;
    }
    // W2b: [0,1536)=Wih2, [1536,2560)=Whh2
    const size_t m4 = (size_t)2560 * 4096 / 4;
    for (size_t e = gid; e < m4; e += (size_t)NWG * 256) {
      size_t idx = e * 4;
      int k = (int)(idx >> 12), n = (int)(idx & 4095);
      const float* src = (k < 1536) ? Wih2 + (size_t)k * 4096 + n
                                    : Whh2 + (size_t)(k - 1536) * 4096 + n;
      f4 v = *(const f4*)src;
      u32x2 p;
      p.x = (uint_)f2b(v.x) | ((uint_)f2b(v.y) << 16);
      p.y = (uint_)f2b(v.z) | ((uint_)f2b(v.w) << 16);
      *(u32x2*)&g_W2b[idx] = p;
    }
  }
  for (int j = wg; j < 64 * 75; j += NWG) {
    prenet_job(s, j, tid, DT, pW0, pW1);
    __syncthreads();
  }
  for (int j = wg; j < 64 * 64; j += NWG) {
    pm_job(s, j, tid, memory, memW);
    __syncthreads();
  }
  grid_sync_full(++ep, wg, tid);

  // ---- 600 decoder steps ----
#pragma unroll 1
  for (int t = 0; t < TDEC; ++t) {
    const int pp = t & 1;
    const float* h1pT = g_h1T[pp];
    float* h1nT = g_h1T[1 - pp];
    const float* h2pT = g_h2T[pp];   // h2(t-1), written below in PA
    const float* dallT = g_dallT + (size_t)t * PRE * BB;

    // PA: gemm1 (32 nt x 4 ks, ksl=448) || reduce2(t-1)
    if (wg < 128) {
      gemm_job<1>(s, tid, wg & 31, wg >> 5, (wg >> 5) * 448, 448,
                  g_W1b, dallT, g_ctxT, h1pT);
    } else if (wg < 192 && t > 0) {
      reduce_lstm_job(wg - 128, tid, 4, 12, bih2, bhh2, g_c2T, g_h2T[pp]);
    }
    grid_sync(++ep, wg, tid);

    // PB: reduce1 -> h1n || proj(t-1)
    if (wg < 64) {
      reduce_lstm_job(wg, tid, 0, 4, bih1, bhh1, g_c1T, h1nT);
    } else if (wg < 128 && t > 0) {
      proj_job(s, wg - 64, tid, h2pT, projW, gateW, gateB, out_mel, out_gate, t - 1);
    }
    grid_sync(++ep, wg, tid);

    // PC: pq(h1n) || gemm2 h2p-slices (K 1536..2560, 4 x 256)
    if (wg < 64) {
      pq_job(s, wg, tid, h1nT, qW);
    } else if (wg < 192) {
      int w = wg - 64;
      gemm_job<2>(s, tid, w & 31, 4 + (w >> 5), 1536 + (w >> 5) * 256, 256,
                  g_W2b, h1nT, g_ctxT, h2pT);
    }
    grid_sync(++ep, wg, tid);

    // PD: energies || gemm2 h1n-slices (K 0..1024, 4 x 256)
    if (wg < 128) {
      energies_job(s, wg, tid, convW, locW, wW, wb, mlen);
    } else if (wg < 256) {
      int w = wg - 128;
      gemm_job<2>(s, tid, w & 31, 8 + (w >> 5), (w >> 5) * 256, 256,
                  g_W2b, h1nT, g_ctxT, h2pT);
    }
    grid_sync(++ep, wg, tid);

    // PE: softmax + ctx
    if (wg < 256) softmax_job(s, wg, tid, memory, out_al, t);
    grid_sync(++ep, wg, tid);

    // PF: gemm2 ctx-slices (K 1024..1536, 4 x 128)
    if (wg < 128) {
      gemm_job<2>(s, tid, wg & 31, 12 + (wg >> 5), 1024 + (wg >> 5) * 128, 128,
                  g_W2b, h1nT, g_ctxT, h2pT);
    }
    grid_sync(++ep, wg, tid);
  }

  // tail: reduce2(599) -> g_h2T[0], then proj(599)
  if (wg < 64) reduce_lstm_job(wg, tid, 4, 12, bih2, bhh2, g_c2T, g_h2T[0]);
  grid_sync(++ep, wg, tid);
  if (wg < 64) proj_job(s, wg, tid, g_h2T[0], projW, gateW, gateB, out_mel, out_gate, TDEC - 1);
  if (wg == 0 && tid == 0)
    __hip_atomic_store(&g_epoch_base, ep, __ATOMIC_RELAXED, __HIP_MEMORY_SCOPE_AGENT);
}

extern "C" void kernel_launch(void* const* d_in, const int* in_sizes, int n_in,
                              void* d_out, int out_size, void* d_ws, size_t ws_size,
                              hipStream_t stream) {
  const float* memory = (const float*)d_in[0];
  const int* mlen = (const int*)d_in[1];
  const float* DT = (const float*)d_in[2];
  const float* qW = (const float*)d_in[3];
  const float* memW = (const float*)d_in[4];
  const float* locW = (const float*)d_in[5];
  const float* convW = (const float*)d_in[6];
  const float* wW = (const float*)d_in[7];
  const float* wb = (const float*)d_in[8];
  const float* pW0 = (const float*)d_in[9];
  const float* pW1 = (const float*)d_in[10];
  const float* Wih1 = (const float*)d_in[11];
  const float* Whh1 = (const float*)d_in[12];
  const float* bih1 = (const float*)d_in[13];
  const float* bhh1 = (const float*)d_in[14];
  const float* Wih2 = (const float*)d_in[15];
  const float* Whh2 = (const float*)d_in[16];
  const float* bih2 = (const float*)d_in[17];
  const float* bhh2 = (const float*)d_in[18];
  const float* projW = (const float*)d_in[19];
  const float* gateW = (const float*)d_in[20];
  const float* gateB = (const float*)d_in[21];
  (void)in_sizes; (void)n_in; (void)out_size; (void)d_ws; (void)ws_size;

  float* out_mel = (float*)d_out;
  float* out_gate = out_mel + (size_t)BB * MEL * TDEC;
  float* out_al = out_gate + (size_t)BB * TDEC;

  k_mega<<<NWG, 256, 0, stream>>>(memory, mlen, DT, qW, memW, locW, convW, wW,
                                  wb, pW0, pW1, Wih1, Whh1, bih1, bhh1, Wih2,
                                  Whh2, bih2, bhh2, projW, gateW, gateB,
                                  out_mel, out_gate, out_al);
}